// Round 4
// baseline (936.661 us; speedup 1.0000x reference)
//
#include <hip/hip_runtime.h>
#include <hip/hip_bf16.h>

// Problem constants (from reference)
constexpr int NN   = 100000;   // nodes
constexpr int IND  = 256;      // input dim
constexpr int HIDD = 256;      // hidden dim
constexpr int EMBD = 64;       // embedding dim
constexpr int EE   = 3200000;  // edges
// CSR bucket partition: RPB rows per bucket
constexpr int RPB  = 49;
constexpr int NBKT = (NN + RPB - 1) / RPB;  // 2041
#define EPS_BN 1e-3f

typedef short  short8  __attribute__((ext_vector_type(8)));
typedef float  floatx4 __attribute__((ext_vector_type(4)));

static __device__ __forceinline__ unsigned short f2bf(float f) {
  __hip_bfloat16 b = __float2bfloat16(f);
  union { __hip_bfloat16 b; unsigned short u; } cv;
  cv.b = b;
  return cv.u;
}
static __device__ __forceinline__ float bf2f(unsigned short u) {
  return __uint_as_float(((unsigned)u) << 16);
}
static __device__ __forceinline__ unsigned char f2fp8(float f) {
  // v_cvt_pk_fp8_f32: OCP e4m3fn on gfx950
  return (unsigned char)__builtin_amdgcn_cvt_pk_fp8_f32(f, f, 0, false);
}

// ---------------- cast x: f32 -> bf16 (row-major unchanged) -----------------
__global__ __launch_bounds__(256) void cast_x_kernel(
    const float* __restrict__ x, unsigned short* __restrict__ xb) {
  const int i = blockIdx.x * blockDim.x + threadIdx.x;  // over 6.4M float4s
  float4 v = ((const float4*)x)[i];
  ushort4 o;
  o.x = f2bf(v.x); o.y = f2bf(v.y); o.z = f2bf(v.z); o.w = f2bf(v.w);
  ((ushort4*)xb)[i] = o;
}

// ---- swizzle weights into MFMA B-fragment layout -----------------------------
// frag id f = kt*NT + nt. Lane l supplies B[k=kt*32+(l>>4)*8+j][n=nt*16+(l&15)],
// stored contiguously: out[(f*64 + l)*8 + j]  ->  one 16B read per frag.
__global__ __launch_bounds__(256) void swz_w1_kernel(
    const float* __restrict__ w1, unsigned short* __restrict__ w1s) {
  const int t = blockIdx.x * blockDim.x + threadIdx.x;  // 8192 threads
  const int lane = t & 63;
  const int f = t >> 6;          // 0..127
  const int kt = f >> 4;         // 0..7
  const int nt = f & 15;         // 0..15
  const int n = nt * 16 + (lane & 15);
#pragma unroll
  for (int j = 0; j < 8; ++j) {
    const int k = kt * 32 + (lane >> 4) * 8 + j;
    w1s[(size_t)(f * 64 + lane) * 8 + j] = f2bf(w1[k * HIDD + n]);
  }
}

__global__ __launch_bounds__(256) void swz_w2_kernel(
    const float* __restrict__ w2, unsigned short* __restrict__ w2s) {
  const int t = blockIdx.x * blockDim.x + threadIdx.x;  // 2048 threads
  const int lane = t & 63;
  const int f = t >> 6;          // 0..31
  const int kt = f >> 2;         // 0..7
  const int nt = f & 3;          // 0..3
  const int n = nt * 16 + (lane & 15);
#pragma unroll
  for (int j = 0; j < 8; ++j) {
    const int k = kt * 32 + (lane >> 4) * 8 + j;
    w2s[(size_t)(f * 64 + lane) * 8 + j] = f2bf(w2[k * EMBD + n]);
  }
}

// ---------------- GEMM1 (MFMA): h0(fp8) = xb @ w1  [100000x256 @ 256x256] ----
__global__ __launch_bounds__(512) void gemm1_mfma(
    const unsigned short* __restrict__ xb, const unsigned short* __restrict__ w1s,
    unsigned char* __restrict__ h0) {
  const int lane = threadIdx.x & 63;
  const int wave = threadIdx.x >> 6;   // 0..7
  const int quad = lane >> 4;
  const int l15  = lane & 15;
  const short8* w1v = (const short8*)w1s;
  short8 bf[2][8];
#pragma unroll
  for (int nt2 = 0; nt2 < 2; ++nt2)
#pragma unroll
    for (int kt = 0; kt < 8; ++kt)
      bf[nt2][kt] = w1v[(size_t)(kt * 16 + wave * 2 + nt2) * 64 + lane];
  for (int i = 0; i < 10; ++i) {
    const int m0 = (blockIdx.x * 10 + i) * 16;
    const unsigned short* ap = xb + (size_t)(m0 + l15) * IND + quad * 8;
    short8 af[8];
#pragma unroll
    for (int kt = 0; kt < 8; ++kt)
      af[kt] = *(const short8*)(ap + kt * 32);
    floatx4 c0 = {0.f, 0.f, 0.f, 0.f};
    floatx4 c1 = {0.f, 0.f, 0.f, 0.f};
#pragma unroll
    for (int kt = 0; kt < 8; ++kt) {
      c0 = __builtin_amdgcn_mfma_f32_16x16x32_bf16(af[kt], bf[0][kt], c0, 0, 0, 0);
      c1 = __builtin_amdgcn_mfma_f32_16x16x32_bf16(af[kt], bf[1][kt], c1, 0, 0, 0);
    }
    // C/D layout: col = lane&15, row = quad*4 + reg  [verified m89/m91]
    unsigned char* o = h0 + (size_t)(m0 + quad * 4) * HIDD + wave * 32 + l15;
#pragma unroll
    for (int r = 0; r < 4; ++r) {
      o[(size_t)r * HIDD]      = f2fp8(c0[r]);
      o[(size_t)r * HIDD + 16] = f2fp8(c1[r]);
    }
  }
}

// ---------------- GEMM2 (MFMA): z0(bf16) = h(bf16) @ w2  [100000x256 @ 256x64]
__global__ __launch_bounds__(256) void gemm2_mfma(
    const unsigned short* __restrict__ hb, const unsigned short* __restrict__ w2s,
    unsigned short* __restrict__ z0) {
  const int lane = threadIdx.x & 63;
  const int wave = threadIdx.x >> 6;   // 0..3
  const int quad = lane >> 4;
  const int l15  = lane & 15;
  const short8* w2v = (const short8*)w2s;
  short8 bf[8];
#pragma unroll
  for (int kt = 0; kt < 8; ++kt)
    bf[kt] = w2v[(size_t)(kt * 4 + wave) * 64 + lane];
  for (int i = 0; i < 10; ++i) {
    const int m0 = (blockIdx.x * 10 + i) * 16;
    const unsigned short* ap = hb + (size_t)(m0 + l15) * HIDD + quad * 8;
    short8 af[8];
#pragma unroll
    for (int kt = 0; kt < 8; ++kt)
      af[kt] = *(const short8*)(ap + kt * 32);
    floatx4 c = {0.f, 0.f, 0.f, 0.f};
#pragma unroll
    for (int kt = 0; kt < 8; ++kt)
      c = __builtin_amdgcn_mfma_f32_16x16x32_bf16(af[kt], bf[kt], c, 0, 0, 0);
    unsigned short* o = z0 + (size_t)(m0 + quad * 4) * EMBD + wave * 16 + l15;
#pragma unroll
    for (int r = 0; r < 4; ++r) o[(size_t)r * EMBD] = f2bf(c[r]);
  }
}

// ---------------- CSR build --------------------------------------------------
__global__ void hist_kernel(const int* __restrict__ row, int* __restrict__ cnt) {
  int e = blockIdx.x * blockDim.x + threadIdx.x;
  if (e < EE) atomicAdd(&cnt[row[e]], 1);
}

__global__ __launch_bounds__(1024) void scan1_kernel(
    const int* __restrict__ cnt, int* __restrict__ tmp, int* __restrict__ bsum) {
  __shared__ int lds[1024];
  int gid = blockIdx.x * 1024 + threadIdx.x;
  int v = (gid < NN) ? cnt[gid] : 0;
  lds[threadIdx.x] = v;
  for (int off = 1; off < 1024; off <<= 1) {
    __syncthreads();
    int t = (threadIdx.x >= off) ? lds[threadIdx.x - off] : 0;
    __syncthreads();
    lds[threadIdx.x] += t;
  }
  __syncthreads();
  if (gid < NN) tmp[gid] = lds[threadIdx.x];
  if (threadIdx.x == 1023) bsum[blockIdx.x] = lds[1023];
}

__global__ __launch_bounds__(128) void scan2_kernel(
    const int* __restrict__ bsum, int* __restrict__ bpre) {
  __shared__ int lds[128];
  const int nb = (NN + 1023) / 1024;  // 98
  int v = (threadIdx.x < nb) ? bsum[threadIdx.x] : 0;
  lds[threadIdx.x] = v;
  for (int off = 1; off < 128; off <<= 1) {
    __syncthreads();
    int t = (threadIdx.x >= off) ? lds[threadIdx.x - off] : 0;
    __syncthreads();
    lds[threadIdx.x] += t;
  }
  __syncthreads();
  if (threadIdx.x < nb) bpre[threadIdx.x] = lds[threadIdx.x] - v;  // exclusive
}

__global__ __launch_bounds__(1024) void scan3_kernel(
    const int* __restrict__ tmp, const int* __restrict__ cnt,
    const int* __restrict__ bpre, int* __restrict__ row_start) {
  int gid = blockIdx.x * 1024 + threadIdx.x;
  if (gid < NN) {
    int ex = tmp[gid] - cnt[gid] + bpre[blockIdx.x];  // exclusive scan
    row_start[gid] = ex;
  }
  if (gid == 0) row_start[NN] = EE;
}

// bucket cursors = row_start at bucket boundaries; padded 1 per 64B line
__global__ __launch_bounds__(256) void init_bcur_kernel(
    const int* __restrict__ row_start, int* __restrict__ bcur) {
  int b = blockIdx.x * blockDim.x + threadIdx.x;
  if (b < NBKT) bcur[b * 16] = row_start[b * RPB];
}

// Pass A: partition edges into row-buckets, writing into the bucket's final
// CSR index range (unsorted within bucket). Frontier = NBKT lines -> L2-hot.
__global__ void partA_kernel(
    const int* __restrict__ row, const int* __restrict__ col,
    const float* __restrict__ val, int* __restrict__ bcur,
    int* __restrict__ rows_tmp, int2* __restrict__ edges_tmp) {
  int e = blockIdx.x * blockDim.x + threadIdx.x;
  if (e < EE) {
    int r = row[e];
    int b = (unsigned)r / (unsigned)RPB;
    int p = atomicAdd(&bcur[b * 16], 1);
    rows_tmp[p] = r;
    int2 pk; pk.x = col[e]; pk.y = __float_as_int(val[e]);
    edges_tmp[p] = pk;
  }
}

// Pass B: one block per bucket; LDS row-cursors; sort bucket into final CSR.
// Destination window ~12KB -> L2-hot, full-line writebacks.
__global__ __launch_bounds__(256) void partB_kernel(
    const int* __restrict__ row_start, const int* __restrict__ rows_tmp,
    const int2* __restrict__ edges_tmp, int2* __restrict__ edges) {
  __shared__ int cur[RPB];
  const int b  = blockIdx.x;
  const int r0 = b * RPB;
  const int rn = (NN - r0 < RPB) ? (NN - r0) : RPB;
  const int s  = row_start[r0];
  const int e  = row_start[(r0 + RPB < NN) ? (r0 + RPB) : NN];
  if (threadIdx.x < rn) cur[threadIdx.x] = row_start[r0 + threadIdx.x];
  __syncthreads();
  for (int p = s + threadIdx.x; p < e; p += 256) {
    int r = rows_tmp[p];
    int q = atomicAdd(&cur[r - r0], 1);
    edges[q] = edges_tmp[p];
  }
}

// ---------------- SpMM1 + BN1 + ReLU: h(bf16) = relu(bn1(A @ h0(fp8))) -------
__global__ __launch_bounds__(256) void spmm1_kernel(
    const unsigned char* __restrict__ h0, const int* __restrict__ row_start,
    const int2* __restrict__ edges,
    const float* __restrict__ gamma, const float* __restrict__ beta,
    const float* __restrict__ mean, const float* __restrict__ var,
    unsigned short* __restrict__ h) {
  const int row  = (blockIdx.x * blockDim.x + threadIdx.x) >> 6;
  const int lane = threadIdx.x & 63;
  const int s = row_start[row];
  const int e = row_start[row + 1];
  float a0 = 0.f, a1 = 0.f, a2 = 0.f, a3 = 0.f;
  int p = s;
  for (; p + 4 <= e; p += 4) {
    int2 e0 = edges[p];
    int2 e1 = edges[p + 1];
    int2 e2 = edges[p + 2];
    int2 e3 = edges[p + 3];
    unsigned g0 = *(const unsigned*)(h0 + (size_t)e0.x * HIDD + lane * 4);
    unsigned g1 = *(const unsigned*)(h0 + (size_t)e1.x * HIDD + lane * 4);
    unsigned g2 = *(const unsigned*)(h0 + (size_t)e2.x * HIDD + lane * 4);
    unsigned g3 = *(const unsigned*)(h0 + (size_t)e3.x * HIDD + lane * 4);
    const float v0 = __int_as_float(e0.y);
    const float v1 = __int_as_float(e1.y);
    const float v2 = __int_as_float(e2.y);
    const float v3 = __int_as_float(e3.y);
    a0 = fmaf(v0, __builtin_amdgcn_cvt_f32_fp8(g0, 0), a0);
    a1 = fmaf(v0, __builtin_amdgcn_cvt_f32_fp8(g0, 1), a1);
    a2 = fmaf(v0, __builtin_amdgcn_cvt_f32_fp8(g0, 2), a2);
    a3 = fmaf(v0, __builtin_amdgcn_cvt_f32_fp8(g0, 3), a3);
    a0 = fmaf(v1, __builtin_amdgcn_cvt_f32_fp8(g1, 0), a0);
    a1 = fmaf(v1, __builtin_amdgcn_cvt_f32_fp8(g1, 1), a1);
    a2 = fmaf(v1, __builtin_amdgcn_cvt_f32_fp8(g1, 2), a2);
    a3 = fmaf(v1, __builtin_amdgcn_cvt_f32_fp8(g1, 3), a3);
    a0 = fmaf(v2, __builtin_amdgcn_cvt_f32_fp8(g2, 0), a0);
    a1 = fmaf(v2, __builtin_amdgcn_cvt_f32_fp8(g2, 1), a1);
    a2 = fmaf(v2, __builtin_amdgcn_cvt_f32_fp8(g2, 2), a2);
    a3 = fmaf(v2, __builtin_amdgcn_cvt_f32_fp8(g2, 3), a3);
    a0 = fmaf(v3, __builtin_amdgcn_cvt_f32_fp8(g3, 0), a0);
    a1 = fmaf(v3, __builtin_amdgcn_cvt_f32_fp8(g3, 1), a1);
    a2 = fmaf(v3, __builtin_amdgcn_cvt_f32_fp8(g3, 2), a2);
    a3 = fmaf(v3, __builtin_amdgcn_cvt_f32_fp8(g3, 3), a3);
  }
  for (; p < e; ++p) {
    int2 e0 = edges[p];
    unsigned g0 = *(const unsigned*)(h0 + (size_t)e0.x * HIDD + lane * 4);
    const float v0 = __int_as_float(e0.y);
    a0 = fmaf(v0, __builtin_amdgcn_cvt_f32_fp8(g0, 0), a0);
    a1 = fmaf(v0, __builtin_amdgcn_cvt_f32_fp8(g0, 1), a1);
    a2 = fmaf(v0, __builtin_amdgcn_cvt_f32_fp8(g0, 2), a2);
    a3 = fmaf(v0, __builtin_amdgcn_cvt_f32_fp8(g0, 3), a3);
  }
  const int d = lane * 4;
  float4 g = *(const float4*)(gamma + d);
  float4 b = *(const float4*)(beta + d);
  float4 m = *(const float4*)(mean + d);
  float4 vv = *(const float4*)(var + d);
  ushort4 o;
  o.x = f2bf(fmaxf(fmaf((a0 - m.x) * rsqrtf(vv.x + EPS_BN), g.x, b.x), 0.f));
  o.y = f2bf(fmaxf(fmaf((a1 - m.y) * rsqrtf(vv.y + EPS_BN), g.y, b.y), 0.f));
  o.z = f2bf(fmaxf(fmaf((a2 - m.z) * rsqrtf(vv.z + EPS_BN), g.z, b.z), 0.f));
  o.w = f2bf(fmaxf(fmaf((a3 - m.w) * rsqrtf(vv.w + EPS_BN), g.w, b.w), 0.f));
  *(ushort4*)(h + (size_t)row * HIDD + d) = o;
}

// ---------------- SpMM2 + BN2: out = bn2(A @ z0(bf16)) -----------------------
__global__ __launch_bounds__(256) void spmm2_kernel(
    const unsigned short* __restrict__ z0, const int* __restrict__ row_start,
    const int2* __restrict__ edges,
    const float* __restrict__ gamma, const float* __restrict__ beta,
    const float* __restrict__ mean, const float* __restrict__ var,
    float* __restrict__ out) {
  const int row  = (blockIdx.x * blockDim.x + threadIdx.x) >> 6;
  const int lane = threadIdx.x & 63;
  const int s = row_start[row];
  const int e = row_start[row + 1];
  float acc = 0.f;
  int p = s;
  for (; p + 4 <= e; p += 4) {
    int2 e0 = edges[p];
    int2 e1 = edges[p + 1];
    int2 e2 = edges[p + 2];
    int2 e3 = edges[p + 3];
    unsigned short g0 = z0[(size_t)e0.x * EMBD + lane];
    unsigned short g1 = z0[(size_t)e1.x * EMBD + lane];
    unsigned short g2 = z0[(size_t)e2.x * EMBD + lane];
    unsigned short g3 = z0[(size_t)e3.x * EMBD + lane];
    acc = fmaf(__int_as_float(e0.y), bf2f(g0), acc);
    acc = fmaf(__int_as_float(e1.y), bf2f(g1), acc);
    acc = fmaf(__int_as_float(e2.y), bf2f(g2), acc);
    acc = fmaf(__int_as_float(e3.y), bf2f(g3), acc);
  }
  for (; p < e; ++p) {
    int2 e0 = edges[p];
    acc = fmaf(__int_as_float(e0.y), bf2f(z0[(size_t)e0.x * EMBD + lane]), acc);
  }
  float r = fmaf((acc - mean[lane]) * rsqrtf(var[lane] + EPS_BN), gamma[lane],
                 beta[lane]);
  out[(size_t)row * EMBD + lane] = r;
}

extern "C" void kernel_launch(void* const* d_in, const int* in_sizes, int n_in,
                              void* d_out, int out_size, void* d_ws, size_t ws_size,
                              hipStream_t stream) {
  const float* x        = (const float*)d_in[0];
  const int*   edge_row = (const int*)d_in[1];
  const int*   edge_col = (const int*)d_in[2];
  const float* edge_val = (const float*)d_in[3];
  const float* w1       = (const float*)d_in[4];
  const float* w2       = (const float*)d_in[5];
  const float* gamma1   = (const float*)d_in[6];
  const float* beta1    = (const float*)d_in[7];
  const float* mean1    = (const float*)d_in[8];
  const float* var1     = (const float*)d_in[9];
  const float* gamma2   = (const float*)d_in[10];
  const float* beta2    = (const float*)d_in[11];
  const float* mean2    = (const float*)d_in[12];
  const float* var2     = (const float*)d_in[13];
  float* out = (float*)d_out;

  // Workspace layout (256B aligned). Total ~168 MB.
  char* ws = (char*)d_ws;
  size_t off = 0;
  auto alloc = [&](size_t bytes) -> void* {
    void* p = ws + off;
    off = (off + bytes + 255) & ~(size_t)255;
    return p;
  };
  unsigned short* xb  = (unsigned short*)alloc((size_t)NN * IND * 2);   // 51.2MB
  unsigned char*  h0  = (unsigned char*)alloc((size_t)NN * HIDD);       // 25.6MB fp8
  unsigned short* h   = (unsigned short*)alloc((size_t)NN * HIDD * 2);  // 51.2MB bf16
  // staging aliases h: edges_tmp(25.6MB)+rows_tmp(12.8MB) dead before spmm1 writes h
  int2* edges_tmp = (int2*)h;
  int*  rows_tmp  = (int*)((char*)h + (size_t)EE * 8);
  unsigned short* z0  = (unsigned short*)alloc((size_t)NN * EMBD * 2);  // 12.8MB bf16
  unsigned short* w1s = (unsigned short*)alloc((size_t)IND * HIDD * 2);
  unsigned short* w2s = (unsigned short*)alloc((size_t)HIDD * EMBD * 2);
  int*   cnt      = (int*)alloc((size_t)NN * 4);
  int*   tmp      = (int*)alloc((size_t)NN * 4);
  int*   bsum     = (int*)alloc(128 * 4);
  int*   bpre     = (int*)alloc(128 * 4);
  int*   row_start= (int*)alloc((size_t)(NN + 1) * 4);
  int*   bcur     = (int*)alloc((size_t)NBKT * 16 * 4);                 // 130KB padded
  int2*  edges    = (int2*)alloc((size_t)EE * 8);                       // 25.6MB

  const int nb_scan = (NN + 1023) / 1024;  // 98

  // casts + weight swizzles (independent of CSR build)
  cast_x_kernel<<<(NN * IND / 4) / 256, 256, 0, stream>>>(x, xb);
  swz_w1_kernel<<<8192 / 256, 256, 0, stream>>>(w1, w1s);
  swz_w2_kernel<<<2048 / 256, 256, 0, stream>>>(w2, w2s);

  // CSR build: hist -> scan -> bucketed two-pass partition
  hipMemsetAsync(cnt, 0, (size_t)NN * 4, stream);
  hist_kernel<<<(EE + 255) / 256, 256, 0, stream>>>(edge_row, cnt);
  scan1_kernel<<<nb_scan, 1024, 0, stream>>>(cnt, tmp, bsum);
  scan2_kernel<<<1, 128, 0, stream>>>(bsum, bpre);
  scan3_kernel<<<nb_scan, 1024, 0, stream>>>(tmp, cnt, bpre, row_start);
  init_bcur_kernel<<<(NBKT + 255) / 256, 256, 0, stream>>>(row_start, bcur);
  partA_kernel<<<(EE + 255) / 256, 256, 0, stream>>>(
      edge_row, edge_col, edge_val, bcur, rows_tmp, edges_tmp);
  partB_kernel<<<NBKT, 256, 0, stream>>>(row_start, rows_tmp, edges_tmp, edges);

  // Layer 1: h0 = fp8(xb @ w1) ; h = bf16(relu(bn1(A @ h0)))
  gemm1_mfma<<<625, 512, 0, stream>>>(xb, w1s, h0);
  spmm1_kernel<<<NN / 4, 256, 0, stream>>>(h0, row_start, edges,
                                           gamma1, beta1, mean1, var1, h);
  // Layer 2: z0 = bf16(h @ w2) ; out = bn2(A @ z0)
  gemm2_mfma<<<625, 256, 0, stream>>>(h, w2s, z0);
  spmm2_kernel<<<NN / 4, 256, 0, stream>>>(z0, row_start, edges,
                                           gamma2, beta2, mean2, var2, out);
}

// Round 5
// 729.059 us; speedup vs baseline: 1.2848x; 1.2848x over previous
//
#include <hip/hip_runtime.h>
#include <hip/hip_bf16.h>

// Problem constants (from reference)
constexpr int NN   = 100000;   // nodes
constexpr int IND  = 256;      // input dim
constexpr int HIDD = 256;      // hidden dim
constexpr int EMBD = 64;       // embedding dim
constexpr int EE   = 3200000;  // edges
// CSR coarse partition: bucket = row >> CB (256 rows per bucket)
constexpr int CB    = 8;
constexpr int NB    = ((NN - 1) >> CB) + 1;   // 391
constexpr int NBP   = 512;                    // padded for LDS scan
constexpr int CHUNK = 4096;                   // edges per partA block
constexpr int EPT   = CHUNK / 256;            // 16 edges per thread
constexpr int NCHUNK = (EE + CHUNK - 1) / CHUNK;  // 782
#define EPS_BN 1e-3f

typedef short  short8  __attribute__((ext_vector_type(8)));
typedef float  floatx4 __attribute__((ext_vector_type(4)));

static __device__ __forceinline__ unsigned short f2bf(float f) {
  __hip_bfloat16 b = __float2bfloat16(f);
  union { __hip_bfloat16 b; unsigned short u; } cv;
  cv.b = b;
  return cv.u;
}
static __device__ __forceinline__ float bf2f(unsigned short u) {
  return __uint_as_float(((unsigned)u) << 16);
}
static __device__ __forceinline__ unsigned char f2fp8(float f) {
  // v_cvt_pk_fp8_f32: OCP e4m3fn on gfx950
  return (unsigned char)__builtin_amdgcn_cvt_pk_fp8_f32(f, f, 0, false);
}

// ---------------- cast x: f32 -> bf16 (row-major unchanged) -----------------
__global__ __launch_bounds__(256) void cast_x_kernel(
    const float* __restrict__ x, unsigned short* __restrict__ xb) {
  const int i = blockIdx.x * blockDim.x + threadIdx.x;  // over 6.4M float4s
  float4 v = ((const float4*)x)[i];
  ushort4 o;
  o.x = f2bf(v.x); o.y = f2bf(v.y); o.z = f2bf(v.z); o.w = f2bf(v.w);
  ((ushort4*)xb)[i] = o;
}

// ---- swizzle weights into MFMA B-fragment layout -----------------------------
__global__ __launch_bounds__(256) void swz_w1_kernel(
    const float* __restrict__ w1, unsigned short* __restrict__ w1s) {
  const int t = blockIdx.x * blockDim.x + threadIdx.x;  // 8192 threads
  const int lane = t & 63;
  const int f = t >> 6;          // 0..127
  const int kt = f >> 4;         // 0..7
  const int nt = f & 15;         // 0..15
  const int n = nt * 16 + (lane & 15);
#pragma unroll
  for (int j = 0; j < 8; ++j) {
    const int k = kt * 32 + (lane >> 4) * 8 + j;
    w1s[(size_t)(f * 64 + lane) * 8 + j] = f2bf(w1[k * HIDD + n]);
  }
}

__global__ __launch_bounds__(256) void swz_w2_kernel(
    const float* __restrict__ w2, unsigned short* __restrict__ w2s) {
  const int t = blockIdx.x * blockDim.x + threadIdx.x;  // 2048 threads
  const int lane = t & 63;
  const int f = t >> 6;          // 0..31
  const int kt = f >> 2;         // 0..7
  const int nt = f & 3;          // 0..3
  const int n = nt * 16 + (lane & 15);
#pragma unroll
  for (int j = 0; j < 8; ++j) {
    const int k = kt * 32 + (lane >> 4) * 8 + j;
    w2s[(size_t)(f * 64 + lane) * 8 + j] = f2bf(w2[k * EMBD + n]);
  }
}

// ---------------- GEMM1 (MFMA): h0(fp8) = xb @ w1  [100000x256 @ 256x256] ----
__global__ __launch_bounds__(512) void gemm1_mfma(
    const unsigned short* __restrict__ xb, const unsigned short* __restrict__ w1s,
    unsigned char* __restrict__ h0) {
  const int lane = threadIdx.x & 63;
  const int wave = threadIdx.x >> 6;   // 0..7
  const int quad = lane >> 4;
  const int l15  = lane & 15;
  const short8* w1v = (const short8*)w1s;
  short8 bf[2][8];
#pragma unroll
  for (int nt2 = 0; nt2 < 2; ++nt2)
#pragma unroll
    for (int kt = 0; kt < 8; ++kt)
      bf[nt2][kt] = w1v[(size_t)(kt * 16 + wave * 2 + nt2) * 64 + lane];
  for (int i = 0; i < 10; ++i) {
    const int m0 = (blockIdx.x * 10 + i) * 16;
    const unsigned short* ap = xb + (size_t)(m0 + l15) * IND + quad * 8;
    short8 af[8];
#pragma unroll
    for (int kt = 0; kt < 8; ++kt)
      af[kt] = *(const short8*)(ap + kt * 32);
    floatx4 c0 = {0.f, 0.f, 0.f, 0.f};
    floatx4 c1 = {0.f, 0.f, 0.f, 0.f};
#pragma unroll
    for (int kt = 0; kt < 8; ++kt) {
      c0 = __builtin_amdgcn_mfma_f32_16x16x32_bf16(af[kt], bf[0][kt], c0, 0, 0, 0);
      c1 = __builtin_amdgcn_mfma_f32_16x16x32_bf16(af[kt], bf[1][kt], c1, 0, 0, 0);
    }
    // C/D layout: col = lane&15, row = quad*4 + reg  [verified m89/m91]
    unsigned char* o = h0 + (size_t)(m0 + quad * 4) * HIDD + wave * 32 + l15;
#pragma unroll
    for (int r = 0; r < 4; ++r) {
      o[(size_t)r * HIDD]      = f2fp8(c0[r]);
      o[(size_t)r * HIDD + 16] = f2fp8(c1[r]);
    }
  }
}

// ---------------- GEMM2 (MFMA): z0(bf16) = h(bf16) @ w2  [100000x256 @ 256x64]
__global__ __launch_bounds__(256) void gemm2_mfma(
    const unsigned short* __restrict__ hb, const unsigned short* __restrict__ w2s,
    unsigned short* __restrict__ z0) {
  const int lane = threadIdx.x & 63;
  const int wave = threadIdx.x >> 6;   // 0..3
  const int quad = lane >> 4;
  const int l15  = lane & 15;
  const short8* w2v = (const short8*)w2s;
  short8 bf[8];
#pragma unroll
  for (int kt = 0; kt < 8; ++kt)
    bf[kt] = w2v[(size_t)(kt * 4 + wave) * 64 + lane];
  for (int i = 0; i < 10; ++i) {
    const int m0 = (blockIdx.x * 10 + i) * 16;
    const unsigned short* ap = hb + (size_t)(m0 + l15) * HIDD + quad * 8;
    short8 af[8];
#pragma unroll
    for (int kt = 0; kt < 8; ++kt)
      af[kt] = *(const short8*)(ap + kt * 32);
    floatx4 c = {0.f, 0.f, 0.f, 0.f};
#pragma unroll
    for (int kt = 0; kt < 8; ++kt)
      c = __builtin_amdgcn_mfma_f32_16x16x32_bf16(af[kt], bf[kt], c, 0, 0, 0);
    unsigned short* o = z0 + (size_t)(m0 + quad * 4) * EMBD + wave * 16 + l15;
#pragma unroll
    for (int r = 0; r < 4; ++r) o[(size_t)r * EMBD] = f2bf(c[r]);
  }
}

// ---------------- CSR build --------------------------------------------------
__global__ void hist_kernel(const int* __restrict__ row, int* __restrict__ cnt) {
  int e = blockIdx.x * blockDim.x + threadIdx.x;
  if (e < EE) atomicAdd(&cnt[row[e]], 1);
}

__global__ __launch_bounds__(1024) void scan1_kernel(
    const int* __restrict__ cnt, int* __restrict__ tmp, int* __restrict__ bsum) {
  __shared__ int lds[1024];
  int gid = blockIdx.x * 1024 + threadIdx.x;
  int v = (gid < NN) ? cnt[gid] : 0;
  lds[threadIdx.x] = v;
  for (int off = 1; off < 1024; off <<= 1) {
    __syncthreads();
    int t = (threadIdx.x >= off) ? lds[threadIdx.x - off] : 0;
    __syncthreads();
    lds[threadIdx.x] += t;
  }
  __syncthreads();
  if (gid < NN) tmp[gid] = lds[threadIdx.x];
  if (threadIdx.x == 1023) bsum[blockIdx.x] = lds[1023];
}

__global__ __launch_bounds__(128) void scan2_kernel(
    const int* __restrict__ bsum, int* __restrict__ bpre) {
  __shared__ int lds[128];
  const int nb = (NN + 1023) / 1024;  // 98
  int v = (threadIdx.x < nb) ? bsum[threadIdx.x] : 0;
  lds[threadIdx.x] = v;
  for (int off = 1; off < 128; off <<= 1) {
    __syncthreads();
    int t = (threadIdx.x >= off) ? lds[threadIdx.x - off] : 0;
    __syncthreads();
    lds[threadIdx.x] += t;
  }
  __syncthreads();
  if (threadIdx.x < nb) bpre[threadIdx.x] = lds[threadIdx.x] - v;  // exclusive
}

__global__ __launch_bounds__(1024) void scan3_kernel(
    const int* __restrict__ tmp, const int* __restrict__ cnt,
    const int* __restrict__ bpre, int* __restrict__ row_start) {
  int gid = blockIdx.x * 1024 + threadIdx.x;
  if (gid < NN) {
    int ex = tmp[gid] - cnt[gid] + bpre[blockIdx.x];  // exclusive scan
    row_start[gid] = ex;
  }
  if (gid == 0) row_start[NN] = EE;
}

// bucket cursors = row_start at coarse-bucket boundaries; 1 per 64B line
__global__ __launch_bounds__(256) void init_bcur_kernel(
    const int* __restrict__ row_start, int* __restrict__ bcur) {
  int b = blockIdx.x * blockDim.x + threadIdx.x;
  if (b < NB) bcur[b * 16] = row_start[b << CB];
}

// Pass A: LDS counting-sort each 4096-edge chunk by coarse bucket, then flush
// piecewise-contiguous runs (avg ~10 edges) with ONE global atomic per
// (block,bucket). Record packs (row:17 | col:17 | val_bf16:16) into 8B.
__global__ __launch_bounds__(256) void partA_kernel(
    const int* __restrict__ row, const int* __restrict__ col,
    const float* __restrict__ val, int* __restrict__ bcur,
    unsigned long long* __restrict__ staged) {
  __shared__ unsigned long long sbuf[CHUNK];  // 32 KB
  __shared__ int cnt[NBP];
  __shared__ int scn[NBP];
  __shared__ int cur[NB];
  __shared__ int gofs[NB];
  const int base = blockIdx.x * CHUNK;
  const int lim  = min(EE - base, CHUNK);
  for (int i = threadIdx.x; i < NBP; i += 256) cnt[i] = 0;
  __syncthreads();
  // load + histogram (records kept in registers)
  unsigned long long rec[EPT];
  int bkt[EPT];
#pragma unroll
  for (int j = 0; j < EPT; ++j) {
    const int idx = threadIdx.x + j * 256;
    bkt[j] = -1;
    if (idx < lim) {
      const int e = base + idx;
      const int r = row[e];
      const int c = col[e];
      const unsigned short v = f2bf(val[e]);
      rec[j] = ((unsigned long long)r << 33) | ((unsigned long long)c << 16) | v;
      bkt[j] = r >> CB;
      atomicAdd(&cnt[bkt[j]], 1);
    }
  }
  __syncthreads();
  // inclusive scan of cnt -> scn (512 entries, 2 per thread)
  for (int i = threadIdx.x; i < NBP; i += 256) scn[i] = cnt[i];
  __syncthreads();
  for (int off = 1; off < NBP; off <<= 1) {
    const int i0 = threadIdx.x, i1 = threadIdx.x + 256;
    const int t0 = (i0 >= off) ? scn[i0 - off] : 0;
    const int t1 = (i1 >= off) ? scn[i1 - off] : 0;
    __syncthreads();
    scn[i0] += t0;
    scn[i1] += t1;
    __syncthreads();
  }
  // placement cursors = exclusive start
  for (int b = threadIdx.x; b < NB; b += 256) cur[b] = scn[b] - cnt[b];
  __syncthreads();
  // reorder into LDS (no line granularity in LDS -> scatter is fine)
#pragma unroll
  for (int j = 0; j < EPT; ++j)
    if (bkt[j] >= 0) {
      const int p = atomicAdd(&cur[bkt[j]], 1);
      sbuf[p] = rec[j];
    }
  __syncthreads();
  // reserve global ranges: one atomic per non-empty bucket
  for (int b = threadIdx.x; b < NB; b += 256) {
    const int c = cnt[b];
    const int g = (c > 0) ? atomicAdd(&bcur[b * 16], c) : 0;
    gofs[b] = g - (scn[b] - c);  // out = gofs[b] + local_slot
  }
  __syncthreads();
  // flush: consecutive slots of a bucket -> consecutive global addresses
  for (int s = threadIdx.x; s < lim; s += 256) {
    const unsigned long long rc = sbuf[s];
    const int b = (int)(rc >> (33 + CB));
    staged[(size_t)(gofs[b] + s)] = rc;
  }
}

// Pass B: one block per coarse bucket (256 rows); LDS row-cursors; writes land
// in a block-local ~65KB window (proven-cheap pattern in R4's partB).
__global__ __launch_bounds__(256) void partB_kernel(
    const int* __restrict__ row_start, const unsigned long long* __restrict__ staged,
    int2* __restrict__ edges) {
  __shared__ int cur[1 << CB];
  const int b  = blockIdx.x;
  const int r0 = b << CB;
  const int rn = min(NN - r0, 1 << CB);
  const int s  = row_start[r0];
  const int e  = row_start[min(r0 + (1 << CB), NN)];
  if ((int)threadIdx.x < rn) cur[threadIdx.x] = row_start[r0 + threadIdx.x];
  __syncthreads();
  for (int p = s + threadIdx.x; p < e; p += 256) {
    const unsigned long long rc = staged[p];
    const int r = (int)(rc >> 33);
    const int c = (int)((rc >> 16) & 0x1FFFF);
    const float v = bf2f((unsigned short)(rc & 0xFFFF));
    const int q = atomicAdd(&cur[r - r0], 1);
    int2 pk; pk.x = c; pk.y = __float_as_int(v);
    edges[q] = pk;
  }
}

// ---------------- SpMM1 + BN1 + ReLU: h(bf16) = relu(bn1(A @ h0(fp8))) -------
__global__ __launch_bounds__(256) void spmm1_kernel(
    const unsigned char* __restrict__ h0, const int* __restrict__ row_start,
    const int2* __restrict__ edges,
    const float* __restrict__ gamma, const float* __restrict__ beta,
    const float* __restrict__ mean, const float* __restrict__ var,
    unsigned short* __restrict__ h) {
  const int row  = (blockIdx.x * blockDim.x + threadIdx.x) >> 6;
  const int lane = threadIdx.x & 63;
  const int s = row_start[row];
  const int e = row_start[row + 1];
  float a0 = 0.f, a1 = 0.f, a2 = 0.f, a3 = 0.f;
  int p = s;
  for (; p + 4 <= e; p += 4) {
    int2 e0 = edges[p];
    int2 e1 = edges[p + 1];
    int2 e2 = edges[p + 2];
    int2 e3 = edges[p + 3];
    unsigned g0 = *(const unsigned*)(h0 + (size_t)e0.x * HIDD + lane * 4);
    unsigned g1 = *(const unsigned*)(h0 + (size_t)e1.x * HIDD + lane * 4);
    unsigned g2 = *(const unsigned*)(h0 + (size_t)e2.x * HIDD + lane * 4);
    unsigned g3 = *(const unsigned*)(h0 + (size_t)e3.x * HIDD + lane * 4);
    const float v0 = __int_as_float(e0.y);
    const float v1 = __int_as_float(e1.y);
    const float v2 = __int_as_float(e2.y);
    const float v3 = __int_as_float(e3.y);
    a0 = fmaf(v0, __builtin_amdgcn_cvt_f32_fp8(g0, 0), a0);
    a1 = fmaf(v0, __builtin_amdgcn_cvt_f32_fp8(g0, 1), a1);
    a2 = fmaf(v0, __builtin_amdgcn_cvt_f32_fp8(g0, 2), a2);
    a3 = fmaf(v0, __builtin_amdgcn_cvt_f32_fp8(g0, 3), a3);
    a0 = fmaf(v1, __builtin_amdgcn_cvt_f32_fp8(g1, 0), a0);
    a1 = fmaf(v1, __builtin_amdgcn_cvt_f32_fp8(g1, 1), a1);
    a2 = fmaf(v1, __builtin_amdgcn_cvt_f32_fp8(g1, 2), a2);
    a3 = fmaf(v1, __builtin_amdgcn_cvt_f32_fp8(g1, 3), a3);
    a0 = fmaf(v2, __builtin_amdgcn_cvt_f32_fp8(g2, 0), a0);
    a1 = fmaf(v2, __builtin_amdgcn_cvt_f32_fp8(g2, 1), a1);
    a2 = fmaf(v2, __builtin_amdgcn_cvt_f32_fp8(g2, 2), a2);
    a3 = fmaf(v2, __builtin_amdgcn_cvt_f32_fp8(g2, 3), a3);
    a0 = fmaf(v3, __builtin_amdgcn_cvt_f32_fp8(g3, 0), a0);
    a1 = fmaf(v3, __builtin_amdgcn_cvt_f32_fp8(g3, 1), a1);
    a2 = fmaf(v3, __builtin_amdgcn_cvt_f32_fp8(g3, 2), a2);
    a3 = fmaf(v3, __builtin_amdgcn_cvt_f32_fp8(g3, 3), a3);
  }
  for (; p < e; ++p) {
    int2 e0 = edges[p];
    unsigned g0 = *(const unsigned*)(h0 + (size_t)e0.x * HIDD + lane * 4);
    const float v0 = __int_as_float(e0.y);
    a0 = fmaf(v0, __builtin_amdgcn_cvt_f32_fp8(g0, 0), a0);
    a1 = fmaf(v0, __builtin_amdgcn_cvt_f32_fp8(g0, 1), a1);
    a2 = fmaf(v0, __builtin_amdgcn_cvt_f32_fp8(g0, 2), a2);
    a3 = fmaf(v0, __builtin_amdgcn_cvt_f32_fp8(g0, 3), a3);
  }
  const int d = lane * 4;
  float4 g = *(const float4*)(gamma + d);
  float4 b = *(const float4*)(beta + d);
  float4 m = *(const float4*)(mean + d);
  float4 vv = *(const float4*)(var + d);
  ushort4 o;
  o.x = f2bf(fmaxf(fmaf((a0 - m.x) * rsqrtf(vv.x + EPS_BN), g.x, b.x), 0.f));
  o.y = f2bf(fmaxf(fmaf((a1 - m.y) * rsqrtf(vv.y + EPS_BN), g.y, b.y), 0.f));
  o.z = f2bf(fmaxf(fmaf((a2 - m.z) * rsqrtf(vv.z + EPS_BN), g.z, b.z), 0.f));
  o.w = f2bf(fmaxf(fmaf((a3 - m.w) * rsqrtf(vv.w + EPS_BN), g.w, b.w), 0.f));
  *(ushort4*)(h + (size_t)row * HIDD + d) = o;
}

// ---------------- SpMM2 + BN2: out = bn2(A @ z0(bf16)) -----------------------
__global__ __launch_bounds__(256) void spmm2_kernel(
    const unsigned short* __restrict__ z0, const int* __restrict__ row_start,
    const int2* __restrict__ edges,
    const float* __restrict__ gamma, const float* __restrict__ beta,
    const float* __restrict__ mean, const float* __restrict__ var,
    float* __restrict__ out) {
  const int row  = (blockIdx.x * blockDim.x + threadIdx.x) >> 6;
  const int lane = threadIdx.x & 63;
  const int s = row_start[row];
  const int e = row_start[row + 1];
  float acc = 0.f;
  int p = s;
  for (; p + 4 <= e; p += 4) {
    int2 e0 = edges[p];
    int2 e1 = edges[p + 1];
    int2 e2 = edges[p + 2];
    int2 e3 = edges[p + 3];
    unsigned short g0 = z0[(size_t)e0.x * EMBD + lane];
    unsigned short g1 = z0[(size_t)e1.x * EMBD + lane];
    unsigned short g2 = z0[(size_t)e2.x * EMBD + lane];
    unsigned short g3 = z0[(size_t)e3.x * EMBD + lane];
    acc = fmaf(__int_as_float(e0.y), bf2f(g0), acc);
    acc = fmaf(__int_as_float(e1.y), bf2f(g1), acc);
    acc = fmaf(__int_as_float(e2.y), bf2f(g2), acc);
    acc = fmaf(__int_as_float(e3.y), bf2f(g3), acc);
  }
  for (; p < e; ++p) {
    int2 e0 = edges[p];
    acc = fmaf(__int_as_float(e0.y), bf2f(z0[(size_t)e0.x * EMBD + lane]), acc);
  }
  float r = fmaf((acc - mean[lane]) * rsqrtf(var[lane] + EPS_BN), gamma[lane],
                 beta[lane]);
  out[(size_t)row * EMBD + lane] = r;
}

extern "C" void kernel_launch(void* const* d_in, const int* in_sizes, int n_in,
                              void* d_out, int out_size, void* d_ws, size_t ws_size,
                              hipStream_t stream) {
  const float* x        = (const float*)d_in[0];
  const int*   edge_row = (const int*)d_in[1];
  const int*   edge_col = (const int*)d_in[2];
  const float* edge_val = (const float*)d_in[3];
  const float* w1       = (const float*)d_in[4];
  const float* w2       = (const float*)d_in[5];
  const float* gamma1   = (const float*)d_in[6];
  const float* beta1    = (const float*)d_in[7];
  const float* mean1    = (const float*)d_in[8];
  const float* var1     = (const float*)d_in[9];
  const float* gamma2   = (const float*)d_in[10];
  const float* beta2    = (const float*)d_in[11];
  const float* mean2    = (const float*)d_in[12];
  const float* var2     = (const float*)d_in[13];
  float* out = (float*)d_out;

  // Workspace layout (256B aligned). Total ~168 MB.
  char* ws = (char*)d_ws;
  size_t off = 0;
  auto alloc = [&](size_t bytes) -> void* {
    void* p = ws + off;
    off = (off + bytes + 255) & ~(size_t)255;
    return p;
  };
  unsigned short* xb  = (unsigned short*)alloc((size_t)NN * IND * 2);   // 51.2MB
  unsigned char*  h0  = (unsigned char*)alloc((size_t)NN * HIDD);       // 25.6MB fp8
  unsigned short* h   = (unsigned short*)alloc((size_t)NN * HIDD * 2);  // 51.2MB bf16
  // staged records alias h: 25.6MB, dead before spmm1 writes h
  unsigned long long* staged = (unsigned long long*)h;
  unsigned short* z0  = (unsigned short*)alloc((size_t)NN * EMBD * 2);  // 12.8MB bf16
  unsigned short* w1s = (unsigned short*)alloc((size_t)IND * HIDD * 2);
  unsigned short* w2s = (unsigned short*)alloc((size_t)HIDD * EMBD * 2);
  int*   cnt      = (int*)alloc((size_t)NN * 4);
  int*   tmp      = (int*)alloc((size_t)NN * 4);
  int*   bsum     = (int*)alloc(128 * 4);
  int*   bpre     = (int*)alloc(128 * 4);
  int*   row_start= (int*)alloc((size_t)(NN + 1) * 4);
  int*   bcur     = (int*)alloc((size_t)NB * 16 * 4);                   // 25KB padded
  int2*  edges    = (int2*)alloc((size_t)EE * 8);                       // 25.6MB

  const int nb_scan = (NN + 1023) / 1024;  // 98

  // casts + weight swizzles (independent of CSR build)
  cast_x_kernel<<<(NN * IND / 4) / 256, 256, 0, stream>>>(x, xb);
  swz_w1_kernel<<<8192 / 256, 256, 0, stream>>>(w1, w1s);
  swz_w2_kernel<<<2048 / 256, 256, 0, stream>>>(w2, w2s);

  // CSR build: hist -> scan -> LDS counting-sort partition (A) -> bucket sort (B)
  hipMemsetAsync(cnt, 0, (size_t)NN * 4, stream);
  hist_kernel<<<(EE + 255) / 256, 256, 0, stream>>>(edge_row, cnt);
  scan1_kernel<<<nb_scan, 1024, 0, stream>>>(cnt, tmp, bsum);
  scan2_kernel<<<1, 128, 0, stream>>>(bsum, bpre);
  scan3_kernel<<<nb_scan, 1024, 0, stream>>>(tmp, cnt, bpre, row_start);
  init_bcur_kernel<<<(NB + 255) / 256, 256, 0, stream>>>(row_start, bcur);
  partA_kernel<<<NCHUNK, 256, 0, stream>>>(
      edge_row, edge_col, edge_val, bcur, staged);
  partB_kernel<<<NB, 256, 0, stream>>>(row_start, staged, edges);

  // Layer 1: h0 = fp8(xb @ w1) ; h = bf16(relu(bn1(A @ h0)))
  gemm1_mfma<<<625, 512, 0, stream>>>(xb, w1s, h0);
  spmm1_kernel<<<NN / 4, 256, 0, stream>>>(h0, row_start, edges,
                                           gamma1, beta1, mean1, var1, h);
  // Layer 2: z0 = bf16(h @ w2) ; out = bn2(A @ z0)
  gemm2_mfma<<<625, 256, 0, stream>>>(h, w2s, z0);
  spmm2_kernel<<<NN / 4, 256, 0, stream>>>(z0, row_start, edges,
                                           gamma2, beta2, mean2, var2, out);
}

// Round 6
// 710.407 us; speedup vs baseline: 1.3185x; 1.0263x over previous
//
#include <hip/hip_runtime.h>
#include <hip/hip_bf16.h>

// Problem constants (from reference)
constexpr int NN   = 100000;   // nodes
constexpr int IND  = 256;      // input dim
constexpr int HIDD = 256;      // hidden dim
constexpr int EMBD = 64;       // embedding dim
constexpr int EE   = 3200000;  // edges
// CSR coarse partition: bucket = row >> CB (256 rows per bucket)
constexpr int CB    = 8;
constexpr int NB    = ((NN - 1) >> CB) + 1;   // 391
constexpr int NBP   = 512;                    // padded for LDS scan
constexpr int CHUNK = 4096;                   // edges per partA block
constexpr int EPT   = CHUNK / 256;            // 16 edges per thread
constexpr int NCHUNK = (EE + CHUNK - 1) / CHUNK;  // 782
#define EPS_BN 1e-3f

typedef short  short8  __attribute__((ext_vector_type(8)));
typedef float  floatx4 __attribute__((ext_vector_type(4)));
typedef float  floatx2 __attribute__((ext_vector_type(2)));

static __device__ __forceinline__ unsigned short f2bf(float f) {
  __hip_bfloat16 b = __float2bfloat16(f);
  union { __hip_bfloat16 b; unsigned short u; } cv;
  cv.b = b;
  return cv.u;
}
static __device__ __forceinline__ float bf2f(unsigned short u) {
  return __uint_as_float(((unsigned)u) << 16);
}
static __device__ __forceinline__ unsigned char f2fp8(float f) {
  // v_cvt_pk_fp8_f32: OCP e4m3fn on gfx950
  return (unsigned char)__builtin_amdgcn_cvt_pk_fp8_f32(f, f, 0, false);
}

// ---------------- cast x: f32 -> bf16 (row-major unchanged) -----------------
__global__ __launch_bounds__(256) void cast_x_kernel(
    const float* __restrict__ x, unsigned short* __restrict__ xb) {
  const int i = blockIdx.x * blockDim.x + threadIdx.x;  // over 6.4M float4s
  float4 v = ((const float4*)x)[i];
  ushort4 o;
  o.x = f2bf(v.x); o.y = f2bf(v.y); o.z = f2bf(v.z); o.w = f2bf(v.w);
  ((ushort4*)xb)[i] = o;
}

// ---- swizzle weights into MFMA B-fragment layout -----------------------------
__global__ __launch_bounds__(256) void swz_w1_kernel(
    const float* __restrict__ w1, unsigned short* __restrict__ w1s) {
  const int t = blockIdx.x * blockDim.x + threadIdx.x;  // 8192 threads
  const int lane = t & 63;
  const int f = t >> 6;          // 0..127
  const int kt = f >> 4;         // 0..7
  const int nt = f & 15;         // 0..15
  const int n = nt * 16 + (lane & 15);
#pragma unroll
  for (int j = 0; j < 8; ++j) {
    const int k = kt * 32 + (lane >> 4) * 8 + j;
    w1s[(size_t)(f * 64 + lane) * 8 + j] = f2bf(w1[k * HIDD + n]);
  }
}

__global__ __launch_bounds__(256) void swz_w2_kernel(
    const float* __restrict__ w2, unsigned short* __restrict__ w2s) {
  const int t = blockIdx.x * blockDim.x + threadIdx.x;  // 2048 threads
  const int lane = t & 63;
  const int f = t >> 6;          // 0..31
  const int kt = f >> 2;         // 0..7
  const int nt = f & 3;          // 0..3
  const int n = nt * 16 + (lane & 15);
#pragma unroll
  for (int j = 0; j < 8; ++j) {
    const int k = kt * 32 + (lane >> 4) * 8 + j;
    w2s[(size_t)(f * 64 + lane) * 8 + j] = f2bf(w2[k * EMBD + n]);
  }
}

// ---------------- GEMM1 (MFMA): h0(fp8) = xb @ w1  [100000x256 @ 256x256] ----
__global__ __launch_bounds__(512) void gemm1_mfma(
    const unsigned short* __restrict__ xb, const unsigned short* __restrict__ w1s,
    unsigned char* __restrict__ h0) {
  const int lane = threadIdx.x & 63;
  const int wave = threadIdx.x >> 6;   // 0..7
  const int quad = lane >> 4;
  const int l15  = lane & 15;
  const short8* w1v = (const short8*)w1s;
  short8 bf[2][8];
#pragma unroll
  for (int nt2 = 0; nt2 < 2; ++nt2)
#pragma unroll
    for (int kt = 0; kt < 8; ++kt)
      bf[nt2][kt] = w1v[(size_t)(kt * 16 + wave * 2 + nt2) * 64 + lane];
  for (int i = 0; i < 10; ++i) {
    const int m0 = (blockIdx.x * 10 + i) * 16;
    const unsigned short* ap = xb + (size_t)(m0 + l15) * IND + quad * 8;
    short8 af[8];
#pragma unroll
    for (int kt = 0; kt < 8; ++kt)
      af[kt] = *(const short8*)(ap + kt * 32);
    floatx4 c0 = {0.f, 0.f, 0.f, 0.f};
    floatx4 c1 = {0.f, 0.f, 0.f, 0.f};
#pragma unroll
    for (int kt = 0; kt < 8; ++kt) {
      c0 = __builtin_amdgcn_mfma_f32_16x16x32_bf16(af[kt], bf[0][kt], c0, 0, 0, 0);
      c1 = __builtin_amdgcn_mfma_f32_16x16x32_bf16(af[kt], bf[1][kt], c1, 0, 0, 0);
    }
    // C/D layout: col = lane&15, row = quad*4 + reg  [verified m89/m91]
    unsigned char* o = h0 + (size_t)(m0 + quad * 4) * HIDD + wave * 32 + l15;
#pragma unroll
    for (int r = 0; r < 4; ++r) {
      o[(size_t)r * HIDD]      = f2fp8(c0[r]);
      o[(size_t)r * HIDD + 16] = f2fp8(c1[r]);
    }
  }
}

// ---------------- GEMM2 (MFMA): z0(fp8) = h(bf16) @ w2  [100000x256 @ 256x64]
__global__ __launch_bounds__(256) void gemm2_mfma(
    const unsigned short* __restrict__ hb, const unsigned short* __restrict__ w2s,
    unsigned char* __restrict__ z0) {
  const int lane = threadIdx.x & 63;
  const int wave = threadIdx.x >> 6;   // 0..3
  const int quad = lane >> 4;
  const int l15  = lane & 15;
  const short8* w2v = (const short8*)w2s;
  short8 bf[8];
#pragma unroll
  for (int kt = 0; kt < 8; ++kt)
    bf[kt] = w2v[(size_t)(kt * 4 + wave) * 64 + lane];
  for (int i = 0; i < 10; ++i) {
    const int m0 = (blockIdx.x * 10 + i) * 16;
    const unsigned short* ap = hb + (size_t)(m0 + l15) * HIDD + quad * 8;
    short8 af[8];
#pragma unroll
    for (int kt = 0; kt < 8; ++kt)
      af[kt] = *(const short8*)(ap + kt * 32);
    floatx4 c = {0.f, 0.f, 0.f, 0.f};
#pragma unroll
    for (int kt = 0; kt < 8; ++kt)
      c = __builtin_amdgcn_mfma_f32_16x16x32_bf16(af[kt], bf[kt], c, 0, 0, 0);
    unsigned char* o = z0 + (size_t)(m0 + quad * 4) * EMBD + wave * 16 + l15;
#pragma unroll
    for (int r = 0; r < 4; ++r) o[(size_t)r * EMBD] = f2fp8(c[r]);
  }
}

// ---------------- CSR build --------------------------------------------------
__global__ void hist_kernel(const int* __restrict__ row, int* __restrict__ cnt) {
  int e = blockIdx.x * blockDim.x + threadIdx.x;
  if (e < EE) atomicAdd(&cnt[row[e]], 1);
}

__global__ __launch_bounds__(1024) void scan1_kernel(
    const int* __restrict__ cnt, int* __restrict__ tmp, int* __restrict__ bsum) {
  __shared__ int lds[1024];
  int gid = blockIdx.x * 1024 + threadIdx.x;
  int v = (gid < NN) ? cnt[gid] : 0;
  lds[threadIdx.x] = v;
  for (int off = 1; off < 1024; off <<= 1) {
    __syncthreads();
    int t = (threadIdx.x >= off) ? lds[threadIdx.x - off] : 0;
    __syncthreads();
    lds[threadIdx.x] += t;
  }
  __syncthreads();
  if (gid < NN) tmp[gid] = lds[threadIdx.x];
  if (threadIdx.x == 1023) bsum[blockIdx.x] = lds[1023];
}

__global__ __launch_bounds__(128) void scan2_kernel(
    const int* __restrict__ bsum, int* __restrict__ bpre) {
  __shared__ int lds[128];
  const int nb = (NN + 1023) / 1024;  // 98
  int v = (threadIdx.x < nb) ? bsum[threadIdx.x] : 0;
  lds[threadIdx.x] = v;
  for (int off = 1; off < 128; off <<= 1) {
    __syncthreads();
    int t = (threadIdx.x >= off) ? lds[threadIdx.x - off] : 0;
    __syncthreads();
    lds[threadIdx.x] += t;
  }
  __syncthreads();
  if (threadIdx.x < nb) bpre[threadIdx.x] = lds[threadIdx.x] - v;  // exclusive
}

__global__ __launch_bounds__(1024) void scan3_kernel(
    const int* __restrict__ tmp, const int* __restrict__ cnt,
    const int* __restrict__ bpre, int* __restrict__ row_start) {
  int gid = blockIdx.x * 1024 + threadIdx.x;
  if (gid < NN) {
    int ex = tmp[gid] - cnt[gid] + bpre[blockIdx.x];  // exclusive scan
    row_start[gid] = ex;
  }
  if (gid == 0) row_start[NN] = EE;
}

// bucket cursors = row_start at coarse-bucket boundaries; 1 per 64B line
__global__ __launch_bounds__(256) void init_bcur_kernel(
    const int* __restrict__ row_start, int* __restrict__ bcur) {
  int b = blockIdx.x * blockDim.x + threadIdx.x;
  if (b < NB) bcur[b * 16] = row_start[b << CB];
}

// Pass A: LDS counting-sort each 4096-edge chunk by coarse bucket, then flush
// piecewise-contiguous runs with ONE global atomic per (block,bucket).
// Record packs (row:17 | col:17 | val_bf16:16) into 8B.
__global__ __launch_bounds__(256) void partA_kernel(
    const int* __restrict__ row, const int* __restrict__ col,
    const float* __restrict__ val, int* __restrict__ bcur,
    unsigned long long* __restrict__ staged) {
  __shared__ unsigned long long sbuf[CHUNK];  // 32 KB
  __shared__ int cnt[NBP];
  __shared__ int scn[NBP];
  __shared__ int cur[NB];
  __shared__ int gofs[NB];
  const int base = blockIdx.x * CHUNK;
  const int lim  = min(EE - base, CHUNK);
  for (int i = threadIdx.x; i < NBP; i += 256) cnt[i] = 0;
  __syncthreads();
  // load + histogram (records kept in registers)
  unsigned long long rec[EPT];
  int bkt[EPT];
#pragma unroll
  for (int j = 0; j < EPT; ++j) {
    const int idx = threadIdx.x + j * 256;
    bkt[j] = -1;
    if (idx < lim) {
      const int e = base + idx;
      const int r = row[e];
      const int c = col[e];
      const unsigned short v = f2bf(val[e]);
      rec[j] = ((unsigned long long)r << 33) | ((unsigned long long)c << 16) | v;
      bkt[j] = r >> CB;
      atomicAdd(&cnt[bkt[j]], 1);
    }
  }
  __syncthreads();
  // inclusive scan of cnt -> scn (512 entries, 2 per thread)
  for (int i = threadIdx.x; i < NBP; i += 256) scn[i] = cnt[i];
  __syncthreads();
  for (int off = 1; off < NBP; off <<= 1) {
    const int i0 = threadIdx.x, i1 = threadIdx.x + 256;
    const int t0 = (i0 >= off) ? scn[i0 - off] : 0;
    const int t1 = (i1 >= off) ? scn[i1 - off] : 0;
    __syncthreads();
    scn[i0] += t0;
    scn[i1] += t1;
    __syncthreads();
  }
  // placement cursors = exclusive start
  for (int b = threadIdx.x; b < NB; b += 256) cur[b] = scn[b] - cnt[b];
  __syncthreads();
  // reorder into LDS (no line granularity in LDS -> scatter is fine)
#pragma unroll
  for (int j = 0; j < EPT; ++j)
    if (bkt[j] >= 0) {
      const int p = atomicAdd(&cur[bkt[j]], 1);
      sbuf[p] = rec[j];
    }
  __syncthreads();
  // reserve global ranges: one atomic per non-empty bucket
  for (int b = threadIdx.x; b < NB; b += 256) {
    const int c = cnt[b];
    const int g = (c > 0) ? atomicAdd(&bcur[b * 16], c) : 0;
    gofs[b] = g - (scn[b] - c);  // out = gofs[b] + local_slot
  }
  __syncthreads();
  // flush: consecutive slots of a bucket -> consecutive global addresses
  for (int s = threadIdx.x; s < lim; s += 256) {
    const unsigned long long rc = sbuf[s];
    const int b = (int)(rc >> (33 + CB));
    staged[(size_t)(gofs[b] + s)] = rc;
  }
}

// Pass B: one block per coarse bucket (256 rows); LDS row-cursors; writes land
// in a block-local ~65KB window (proven-cheap pattern).
// Emits (col<<6, val) so spmm kernels skip the index scaling.
__global__ __launch_bounds__(256) void partB_kernel(
    const int* __restrict__ row_start, const unsigned long long* __restrict__ staged,
    int2* __restrict__ edges) {
  __shared__ int cur[1 << CB];
  const int b  = blockIdx.x;
  const int r0 = b << CB;
  const int rn = min(NN - r0, 1 << CB);
  const int s  = row_start[r0];
  const int e  = row_start[min(r0 + (1 << CB), NN)];
  if ((int)threadIdx.x < rn) cur[threadIdx.x] = row_start[r0 + threadIdx.x];
  __syncthreads();
  for (int p = s + threadIdx.x; p < e; p += 256) {
    const unsigned long long rc = staged[p];
    const int r = (int)(rc >> 33);
    const int c = (int)((rc >> 16) & 0x1FFFF);
    const float v = bf2f((unsigned short)(rc & 0xFFFF));
    const int q = atomicAdd(&cur[r - r0], 1);
    int2 pk; pk.x = c << 6; pk.y = __float_as_int(v);  // col*64 pre-scaled
    edges[q] = pk;
  }
}

// ---------------- SpMM1 + BN1 + ReLU: h(bf16) = relu(bn1(A @ h0(fp8))) -------
// One wave per row; lane owns dims 4i..4i+3. Unroll x8, packed fp8->f32 cvt,
// float2 accumulators (v_pk_fma_f32 candidates).
__global__ __launch_bounds__(256) void spmm1_kernel(
    const unsigned char* __restrict__ h0, const int* __restrict__ row_start,
    const int2* __restrict__ edges,
    const float* __restrict__ gamma, const float* __restrict__ beta,
    const float* __restrict__ mean, const float* __restrict__ var,
    unsigned short* __restrict__ h) {
  const int row  = (blockIdx.x * blockDim.x + threadIdx.x) >> 6;
  const int lane = threadIdx.x & 63;
  const int lane4 = lane * 4;
  const int s = row_start[row];
  const int e = row_start[row + 1];
  floatx2 acc01 = {0.f, 0.f};
  floatx2 acc23 = {0.f, 0.f};
  int p = s;
  for (; p + 8 <= e; p += 8) {
    int2 er[8];
    unsigned gg[8];
#pragma unroll
    for (int j = 0; j < 8; ++j) er[j] = edges[p + j];
#pragma unroll
    for (int j = 0; j < 8; ++j)
      gg[j] = *(const unsigned*)(h0 + ((size_t)(unsigned)er[j].x * 4) + lane4);
#pragma unroll
    for (int j = 0; j < 8; ++j) {
      const float v = __int_as_float(er[j].y);
      floatx2 lo = __builtin_amdgcn_cvt_pk_f32_fp8(gg[j], false);
      floatx2 hi = __builtin_amdgcn_cvt_pk_f32_fp8(gg[j], true);
      acc01 += lo * v;
      acc23 += hi * v;
    }
  }
  for (; p < e; ++p) {
    int2 e0 = edges[p];
    unsigned g0 = *(const unsigned*)(h0 + ((size_t)(unsigned)e0.x * 4) + lane4);
    const float v0 = __int_as_float(e0.y);
    floatx2 lo = __builtin_amdgcn_cvt_pk_f32_fp8(g0, false);
    floatx2 hi = __builtin_amdgcn_cvt_pk_f32_fp8(g0, true);
    acc01 += lo * v0;
    acc23 += hi * v0;
  }
  const int d = lane4;
  float4 g = *(const float4*)(gamma + d);
  float4 b = *(const float4*)(beta + d);
  float4 m = *(const float4*)(mean + d);
  float4 vv = *(const float4*)(var + d);
  ushort4 o;
  o.x = f2bf(fmaxf(fmaf((acc01.x - m.x) * rsqrtf(vv.x + EPS_BN), g.x, b.x), 0.f));
  o.y = f2bf(fmaxf(fmaf((acc01.y - m.y) * rsqrtf(vv.y + EPS_BN), g.y, b.y), 0.f));
  o.z = f2bf(fmaxf(fmaf((acc23.x - m.z) * rsqrtf(vv.z + EPS_BN), g.z, b.z), 0.f));
  o.w = f2bf(fmaxf(fmaf((acc23.y - m.w) * rsqrtf(vv.w + EPS_BN), g.w, b.w), 0.f));
  *(ushort4*)(h + (size_t)row * HIDD + d) = o;
}

// ---------------- SpMM2 + BN2: out = bn2(A @ z0(fp8)) ------------------------
// One wave per row; lane = embedding dim; 64B (one line) gather per edge.
__global__ __launch_bounds__(256) void spmm2_kernel(
    const unsigned char* __restrict__ z0, const int* __restrict__ row_start,
    const int2* __restrict__ edges,
    const float* __restrict__ gamma, const float* __restrict__ beta,
    const float* __restrict__ mean, const float* __restrict__ var,
    float* __restrict__ out) {
  const int row  = (blockIdx.x * blockDim.x + threadIdx.x) >> 6;
  const int lane = threadIdx.x & 63;
  const int s = row_start[row];
  const int e = row_start[row + 1];
  float acc = 0.f;
  int p = s;
  for (; p + 8 <= e; p += 8) {
    int2 er[8];
    unsigned char gb[8];
#pragma unroll
    for (int j = 0; j < 8; ++j) er[j] = edges[p + j];
#pragma unroll
    for (int j = 0; j < 8; ++j)
      gb[j] = z0[(size_t)(unsigned)er[j].x + lane];  // er.x = col*64
#pragma unroll
    for (int j = 0; j < 8; ++j)
      acc = fmaf(__int_as_float(er[j].y),
                 __builtin_amdgcn_cvt_f32_fp8((int)gb[j], 0), acc);
  }
  for (; p < e; ++p) {
    int2 e0 = edges[p];
    unsigned char g0 = z0[(size_t)(unsigned)e0.x + lane];
    acc = fmaf(__int_as_float(e0.y), __builtin_amdgcn_cvt_f32_fp8((int)g0, 0), acc);
  }
  float r = fmaf((acc - mean[lane]) * rsqrtf(var[lane] + EPS_BN), gamma[lane],
                 beta[lane]);
  out[(size_t)row * EMBD + lane] = r;
}

extern "C" void kernel_launch(void* const* d_in, const int* in_sizes, int n_in,
                              void* d_out, int out_size, void* d_ws, size_t ws_size,
                              hipStream_t stream) {
  const float* x        = (const float*)d_in[0];
  const int*   edge_row = (const int*)d_in[1];
  const int*   edge_col = (const int*)d_in[2];
  const float* edge_val = (const float*)d_in[3];
  const float* w1       = (const float*)d_in[4];
  const float* w2       = (const float*)d_in[5];
  const float* gamma1   = (const float*)d_in[6];
  const float* beta1    = (const float*)d_in[7];
  const float* mean1    = (const float*)d_in[8];
  const float* var1     = (const float*)d_in[9];
  const float* gamma2   = (const float*)d_in[10];
  const float* beta2    = (const float*)d_in[11];
  const float* mean2    = (const float*)d_in[12];
  const float* var2     = (const float*)d_in[13];
  float* out = (float*)d_out;

  // Workspace layout (256B aligned). Total ~162 MB.
  char* ws = (char*)d_ws;
  size_t off = 0;
  auto alloc = [&](size_t bytes) -> void* {
    void* p = ws + off;
    off = (off + bytes + 255) & ~(size_t)255;
    return p;
  };
  unsigned short* xb  = (unsigned short*)alloc((size_t)NN * IND * 2);   // 51.2MB
  unsigned char*  h0  = (unsigned char*)alloc((size_t)NN * HIDD);       // 25.6MB fp8
  unsigned short* h   = (unsigned short*)alloc((size_t)NN * HIDD * 2);  // 51.2MB bf16
  // staged records alias h: 25.6MB, dead before spmm1 writes h
  unsigned long long* staged = (unsigned long long*)h;
  unsigned char*  z0  = (unsigned char*)alloc((size_t)NN * EMBD);       // 6.4MB fp8
  unsigned short* w1s = (unsigned short*)alloc((size_t)IND * HIDD * 2);
  unsigned short* w2s = (unsigned short*)alloc((size_t)HIDD * EMBD * 2);
  int*   cnt      = (int*)alloc((size_t)NN * 4);
  int*   tmp      = (int*)alloc((size_t)NN * 4);
  int*   bsum     = (int*)alloc(128 * 4);
  int*   bpre     = (int*)alloc(128 * 4);
  int*   row_start= (int*)alloc((size_t)(NN + 1) * 4);
  int*   bcur     = (int*)alloc((size_t)NB * 16 * 4);                   // 25KB padded
  int2*  edges    = (int2*)alloc((size_t)EE * 8);                       // 25.6MB

  const int nb_scan = (NN + 1023) / 1024;  // 98

  // casts + weight swizzles (independent of CSR build)
  cast_x_kernel<<<(NN * IND / 4) / 256, 256, 0, stream>>>(x, xb);
  swz_w1_kernel<<<8192 / 256, 256, 0, stream>>>(w1, w1s);
  swz_w2_kernel<<<2048 / 256, 256, 0, stream>>>(w2, w2s);

  // CSR build: hist -> scan -> LDS counting-sort partition (A) -> bucket sort (B)
  hipMemsetAsync(cnt, 0, (size_t)NN * 4, stream);
  hist_kernel<<<(EE + 255) / 256, 256, 0, stream>>>(edge_row, cnt);
  scan1_kernel<<<nb_scan, 1024, 0, stream>>>(cnt, tmp, bsum);
  scan2_kernel<<<1, 128, 0, stream>>>(bsum, bpre);
  scan3_kernel<<<nb_scan, 1024, 0, stream>>>(tmp, cnt, bpre, row_start);
  init_bcur_kernel<<<(NB + 255) / 256, 256, 0, stream>>>(row_start, bcur);
  partA_kernel<<<NCHUNK, 256, 0, stream>>>(
      edge_row, edge_col, edge_val, bcur, staged);
  partB_kernel<<<NB, 256, 0, stream>>>(row_start, staged, edges);

  // Layer 1: h0 = fp8(xb @ w1) ; h = bf16(relu(bn1(A @ h0)))
  gemm1_mfma<<<625, 512, 0, stream>>>(xb, w1s, h0);
  spmm1_kernel<<<NN / 4, 256, 0, stream>>>(h0, row_start, edges,
                                           gamma1, beta1, mean1, var1, h);
  // Layer 2: z0 = fp8(h @ w2) ; out = bn2(A @ z0)
  gemm2_mfma<<<625, 256, 0, stream>>>(h, w2s, z0);
  spmm2_kernel<<<NN / 4, 256, 0, stream>>>(z0, row_start, edges,
                                           gamma2, beta2, mean2, var2, out);
}

// Round 7
// 650.206 us; speedup vs baseline: 1.4406x; 1.0926x over previous
//
#include <hip/hip_runtime.h>
#include <hip/hip_bf16.h>

// Problem constants (from reference)
constexpr int NN   = 100000;   // nodes
constexpr int IND  = 256;      // input dim
constexpr int HIDD = 256;      // hidden dim
constexpr int EMBD = 64;       // embedding dim
constexpr int EE   = 3200000;  // edges
// CSR coarse partition: bucket = row >> CB (256 rows per bucket)
constexpr int CB    = 8;
constexpr int NB    = ((NN - 1) >> CB) + 1;   // 391
constexpr int NBP   = 512;                    // padded for LDS scan
constexpr int CHUNK = 4096;                   // edges per partA block
constexpr int EPT   = CHUNK / 256;            // 16 edges per thread
constexpr int NCHUNK = (EE + CHUNK - 1) / CHUNK;  // 782
#define EPS_BN 1e-3f

typedef short  short8  __attribute__((ext_vector_type(8)));
typedef float  floatx4 __attribute__((ext_vector_type(4)));
typedef float  floatx2 __attribute__((ext_vector_type(2)));

static __device__ __forceinline__ unsigned short f2bf(float f) {
  __hip_bfloat16 b = __float2bfloat16(f);
  union { __hip_bfloat16 b; unsigned short u; } cv;
  cv.b = b;
  return cv.u;
}
static __device__ __forceinline__ float bf2f(unsigned short u) {
  return __uint_as_float(((unsigned)u) << 16);
}
static __device__ __forceinline__ unsigned char f2fp8(float f) {
  // v_cvt_pk_fp8_f32: OCP e4m3fn on gfx950
  return (unsigned char)__builtin_amdgcn_cvt_pk_fp8_f32(f, f, 0, false);
}

// ---- swizzle weights into MFMA B-fragment layout -----------------------------
__global__ __launch_bounds__(256) void swz_w1_kernel(
    const float* __restrict__ w1, unsigned short* __restrict__ w1s) {
  const int t = blockIdx.x * blockDim.x + threadIdx.x;  // 8192 threads
  const int lane = t & 63;
  const int f = t >> 6;          // 0..127
  const int kt = f >> 4;         // 0..7
  const int nt = f & 15;         // 0..15
  const int n = nt * 16 + (lane & 15);
#pragma unroll
  for (int j = 0; j < 8; ++j) {
    const int k = kt * 32 + (lane >> 4) * 8 + j;
    w1s[(size_t)(f * 64 + lane) * 8 + j] = f2bf(w1[k * HIDD + n]);
  }
}

__global__ __launch_bounds__(256) void swz_w2_kernel(
    const float* __restrict__ w2, unsigned short* __restrict__ w2s) {
  const int t = blockIdx.x * blockDim.x + threadIdx.x;  // 2048 threads
  const int lane = t & 63;
  const int f = t >> 6;          // 0..31
  const int kt = f >> 2;         // 0..7
  const int nt = f & 3;          // 0..3
  const int n = nt * 16 + (lane & 15);
#pragma unroll
  for (int j = 0; j < 8; ++j) {
    const int k = kt * 32 + (lane >> 4) * 8 + j;
    w2s[(size_t)(f * 64 + lane) * 8 + j] = f2bf(w2[k * EMBD + n]);
  }
}

// ---------------- GEMM1 (MFMA): h0(fp8) = bf16(x) @ w1 -----------------------
// Reads x as f32 and converts in-register (same rounding as the old cast pass).
__global__ __launch_bounds__(512) void gemm1_mfma(
    const float* __restrict__ x, const unsigned short* __restrict__ w1s,
    unsigned char* __restrict__ h0) {
  const int lane = threadIdx.x & 63;
  const int wave = threadIdx.x >> 6;   // 0..7
  const int quad = lane >> 4;
  const int l15  = lane & 15;
  const short8* w1v = (const short8*)w1s;
  short8 bf[2][8];
#pragma unroll
  for (int nt2 = 0; nt2 < 2; ++nt2)
#pragma unroll
    for (int kt = 0; kt < 8; ++kt)
      bf[nt2][kt] = w1v[(size_t)(kt * 16 + wave * 2 + nt2) * 64 + lane];
  for (int i = 0; i < 10; ++i) {
    const int m0 = (blockIdx.x * 10 + i) * 16;
    const float* ap = x + (size_t)(m0 + l15) * IND + quad * 8;
    short8 af[8];
#pragma unroll
    for (int kt = 0; kt < 8; ++kt) {
      float4 f0 = *(const float4*)(ap + kt * 32);
      float4 f1 = *(const float4*)(ap + kt * 32 + 4);
      short8 a;
      a[0] = (short)f2bf(f0.x); a[1] = (short)f2bf(f0.y);
      a[2] = (short)f2bf(f0.z); a[3] = (short)f2bf(f0.w);
      a[4] = (short)f2bf(f1.x); a[5] = (short)f2bf(f1.y);
      a[6] = (short)f2bf(f1.z); a[7] = (short)f2bf(f1.w);
      af[kt] = a;
    }
    floatx4 c0 = {0.f, 0.f, 0.f, 0.f};
    floatx4 c1 = {0.f, 0.f, 0.f, 0.f};
#pragma unroll
    for (int kt = 0; kt < 8; ++kt) {
      c0 = __builtin_amdgcn_mfma_f32_16x16x32_bf16(af[kt], bf[0][kt], c0, 0, 0, 0);
      c1 = __builtin_amdgcn_mfma_f32_16x16x32_bf16(af[kt], bf[1][kt], c1, 0, 0, 0);
    }
    // C/D layout: col = lane&15, row = quad*4 + reg  [verified m89/m91]
    unsigned char* o = h0 + (size_t)(m0 + quad * 4) * HIDD + wave * 32 + l15;
#pragma unroll
    for (int r = 0; r < 4; ++r) {
      o[(size_t)r * HIDD]      = f2fp8(c0[r]);
      o[(size_t)r * HIDD + 16] = f2fp8(c1[r]);
    }
  }
}

// ---------------- GEMM2 (MFMA): z0(fp8) = h(bf16) @ w2 -----------------------
__global__ __launch_bounds__(256) void gemm2_mfma(
    const unsigned short* __restrict__ hb, const unsigned short* __restrict__ w2s,
    unsigned char* __restrict__ z0) {
  const int lane = threadIdx.x & 63;
  const int wave = threadIdx.x >> 6;   // 0..3
  const int quad = lane >> 4;
  const int l15  = lane & 15;
  const short8* w2v = (const short8*)w2s;
  short8 bf[8];
#pragma unroll
  for (int kt = 0; kt < 8; ++kt)
    bf[kt] = w2v[(size_t)(kt * 4 + wave) * 64 + lane];
  for (int i = 0; i < 10; ++i) {
    const int m0 = (blockIdx.x * 10 + i) * 16;
    const unsigned short* ap = hb + (size_t)(m0 + l15) * HIDD + quad * 8;
    short8 af[8];
#pragma unroll
    for (int kt = 0; kt < 8; ++kt)
      af[kt] = *(const short8*)(ap + kt * 32);
    floatx4 c = {0.f, 0.f, 0.f, 0.f};
#pragma unroll
    for (int kt = 0; kt < 8; ++kt)
      c = __builtin_amdgcn_mfma_f32_16x16x32_bf16(af[kt], bf[kt], c, 0, 0, 0);
    unsigned char* o = z0 + (size_t)(m0 + quad * 4) * EMBD + wave * 16 + l15;
#pragma unroll
    for (int r = 0; r < 4; ++r) o[(size_t)r * EMBD] = f2fp8(c[r]);
  }
}

// ---------------- CSR build --------------------------------------------------
// Bucket-level histogram: LDS counters per chunk, <=NB global atomics/chunk.
__global__ __launch_bounds__(256) void histb_kernel(
    const int* __restrict__ row, int* __restrict__ bcnt) {
  __shared__ int lcnt[NB];
  for (int i = threadIdx.x; i < NB; i += 256) lcnt[i] = 0;
  __syncthreads();
  const int base = blockIdx.x * CHUNK;
  const int lim  = min(EE - base, CHUNK);
  for (int i = threadIdx.x; i < lim; i += 256)
    atomicAdd(&lcnt[row[base + i] >> CB], 1);
  __syncthreads();
  for (int i = threadIdx.x; i < NB; i += 256) {
    const int c = lcnt[i];
    if (c) atomicAdd(&bcnt[i * 16], c);
  }
}

// Scan 391 bucket counts -> bucket_start (compact) + bcur (padded cursors)
__global__ __launch_bounds__(512) void bscan_kernel(
    const int* __restrict__ bcnt, int* __restrict__ bucket_start,
    int* __restrict__ bcur) {
  __shared__ int lds[512];
  int v = (threadIdx.x < NB) ? bcnt[threadIdx.x * 16] : 0;
  lds[threadIdx.x] = v;
  for (int off = 1; off < 512; off <<= 1) {
    __syncthreads();
    int t = (threadIdx.x >= off) ? lds[threadIdx.x - off] : 0;
    __syncthreads();
    lds[threadIdx.x] += t;
  }
  __syncthreads();
  if (threadIdx.x < NB) {
    const int excl = lds[threadIdx.x] - v;
    bucket_start[threadIdx.x] = excl;
    bcur[threadIdx.x * 16] = excl;
  }
  if (threadIdx.x == 0) bucket_start[NB] = EE;
}

// Pass A: LDS counting-sort each 4096-edge chunk by coarse bucket, then flush
// piecewise-contiguous runs with ONE global atomic per (block,bucket).
// Record packs (row:17 | col:17 | val_bf16:16) into 8B.
__global__ __launch_bounds__(256) void partA_kernel(
    const int* __restrict__ row, const int* __restrict__ col,
    const float* __restrict__ val, int* __restrict__ bcur,
    unsigned long long* __restrict__ staged) {
  __shared__ unsigned long long sbuf[CHUNK];  // 32 KB
  __shared__ int cnt[NBP];
  __shared__ int scn[NBP];
  __shared__ int cur[NB];
  __shared__ int gofs[NB];
  const int base = blockIdx.x * CHUNK;
  const int lim  = min(EE - base, CHUNK);
  for (int i = threadIdx.x; i < NBP; i += 256) cnt[i] = 0;
  __syncthreads();
  // load + histogram (records kept in registers)
  unsigned long long rec[EPT];
  int bkt[EPT];
#pragma unroll
  for (int j = 0; j < EPT; ++j) {
    const int idx = threadIdx.x + j * 256;
    bkt[j] = -1;
    if (idx < lim) {
      const int e = base + idx;
      const int r = row[e];
      const int c = col[e];
      const unsigned short v = f2bf(val[e]);
      rec[j] = ((unsigned long long)r << 33) | ((unsigned long long)c << 16) | v;
      bkt[j] = r >> CB;
      atomicAdd(&cnt[bkt[j]], 1);
    }
  }
  __syncthreads();
  // inclusive scan of cnt -> scn (512 entries, 2 per thread)
  for (int i = threadIdx.x; i < NBP; i += 256) scn[i] = cnt[i];
  __syncthreads();
  for (int off = 1; off < NBP; off <<= 1) {
    const int i0 = threadIdx.x, i1 = threadIdx.x + 256;
    const int t0 = (i0 >= off) ? scn[i0 - off] : 0;
    const int t1 = (i1 >= off) ? scn[i1 - off] : 0;
    __syncthreads();
    scn[i0] += t0;
    scn[i1] += t1;
    __syncthreads();
  }
  // placement cursors = exclusive start
  for (int b = threadIdx.x; b < NB; b += 256) cur[b] = scn[b] - cnt[b];
  __syncthreads();
  // reorder into LDS (no line granularity in LDS -> scatter is fine)
#pragma unroll
  for (int j = 0; j < EPT; ++j)
    if (bkt[j] >= 0) {
      const int p = atomicAdd(&cur[bkt[j]], 1);
      sbuf[p] = rec[j];
    }
  __syncthreads();
  // reserve global ranges: one atomic per non-empty bucket
  for (int b = threadIdx.x; b < NB; b += 256) {
    const int c = cnt[b];
    const int g = (c > 0) ? atomicAdd(&bcur[b * 16], c) : 0;
    gofs[b] = g - (scn[b] - c);  // out = gofs[b] + local_slot
  }
  __syncthreads();
  // flush: consecutive slots of a bucket -> consecutive global addresses
  for (int s = threadIdx.x; s < lim; s += 256) {
    const unsigned long long rc = sbuf[s];
    const int b = (int)(rc >> (33 + CB));
    staged[(size_t)(gofs[b] + s)] = rc;
  }
}

// Pass B: one block per coarse bucket (256 rows). Pass 1 histograms rows
// (high-dword reads) -> LDS scan -> writes row_start + cursors. Pass 2
// scatters records into the block-local ~65KB window (L2-hot on re-read).
__global__ __launch_bounds__(256) void partB_kernel(
    const int* __restrict__ bucket_start,
    const unsigned long long* __restrict__ staged,
    int2* __restrict__ edges, int* __restrict__ row_start) {
  __shared__ int cnt[1 << CB];
  __shared__ int ofs[1 << CB];
  const int b  = blockIdx.x;
  const int r0 = b << CB;
  const int rn = min(NN - r0, 1 << CB);
  const int s  = bucket_start[b];
  const int e  = bucket_start[b + 1];
  cnt[threadIdx.x] = 0;
  __syncthreads();
  // pass 1: row histogram (read only the high dword of each record)
  const unsigned* hi = (const unsigned*)staged;
  for (int p = s + threadIdx.x; p < e; p += 256) {
    const unsigned hw = hi[2 * p + 1];
    const int r = (int)((hw >> 1) & 0x1FFFF);
    atomicAdd(&cnt[r - r0], 1);
  }
  __syncthreads();
  // exclusive scan of 256 bins
  const int v = cnt[threadIdx.x];
  ofs[threadIdx.x] = v;
  for (int off = 1; off < 256; off <<= 1) {
    __syncthreads();
    const int t = (threadIdx.x >= off) ? ofs[threadIdx.x - off] : 0;
    __syncthreads();
    ofs[threadIdx.x] += t;
  }
  __syncthreads();
  const int excl = ofs[threadIdx.x] - v;
  if ((int)threadIdx.x < rn) row_start[r0 + threadIdx.x] = s + excl;
  if (b == NB - 1 && threadIdx.x == 0) row_start[NN] = e;
  __syncthreads();
  cnt[threadIdx.x] = s + excl;  // reuse as cursors
  __syncthreads();
  // pass 2: scatter into final CSR order
  for (int p = s + threadIdx.x; p < e; p += 256) {
    const unsigned long long rc = staged[p];
    const int r = (int)(rc >> 33);
    const int c = (int)((rc >> 16) & 0x1FFFF);
    const float vv = bf2f((unsigned short)(rc & 0xFFFF));
    const int q = atomicAdd(&cnt[r - r0], 1);
    int2 pk; pk.x = c << 6; pk.y = __float_as_int(vv);  // col*64 pre-scaled
    edges[q] = pk;
  }
}

// ---------------- SpMM1 + BN1 + ReLU: h(bf16) = relu(bn1(A @ h0(fp8))) -------
__global__ __launch_bounds__(256) void spmm1_kernel(
    const unsigned char* __restrict__ h0, const int* __restrict__ row_start,
    const int2* __restrict__ edges,
    const float* __restrict__ gamma, const float* __restrict__ beta,
    const float* __restrict__ mean, const float* __restrict__ var,
    unsigned short* __restrict__ h) {
  const int row  = (blockIdx.x * blockDim.x + threadIdx.x) >> 6;
  const int lane = threadIdx.x & 63;
  const int lane4 = lane * 4;
  const int s = row_start[row];
  const int e = row_start[row + 1];
  floatx2 acc01 = {0.f, 0.f};
  floatx2 acc23 = {0.f, 0.f};
  int p = s;
  for (; p + 8 <= e; p += 8) {
    int2 er[8];
    unsigned gg[8];
#pragma unroll
    for (int j = 0; j < 8; ++j) er[j] = edges[p + j];
#pragma unroll
    for (int j = 0; j < 8; ++j)
      gg[j] = *(const unsigned*)(h0 + ((size_t)(unsigned)er[j].x * 4) + lane4);
#pragma unroll
    for (int j = 0; j < 8; ++j) {
      const float v = __int_as_float(er[j].y);
      floatx2 lo = __builtin_amdgcn_cvt_pk_f32_fp8(gg[j], false);
      floatx2 hi = __builtin_amdgcn_cvt_pk_f32_fp8(gg[j], true);
      acc01 += lo * v;
      acc23 += hi * v;
    }
  }
  for (; p < e; ++p) {
    int2 e0 = edges[p];
    unsigned g0 = *(const unsigned*)(h0 + ((size_t)(unsigned)e0.x * 4) + lane4);
    const float v0 = __int_as_float(e0.y);
    floatx2 lo = __builtin_amdgcn_cvt_pk_f32_fp8(g0, false);
    floatx2 hi = __builtin_amdgcn_cvt_pk_f32_fp8(g0, true);
    acc01 += lo * v0;
    acc23 += hi * v0;
  }
  const int d = lane4;
  float4 g = *(const float4*)(gamma + d);
  float4 b = *(const float4*)(beta + d);
  float4 m = *(const float4*)(mean + d);
  float4 vv = *(const float4*)(var + d);
  ushort4 o;
  o.x = f2bf(fmaxf(fmaf((acc01.x - m.x) * rsqrtf(vv.x + EPS_BN), g.x, b.x), 0.f));
  o.y = f2bf(fmaxf(fmaf((acc01.y - m.y) * rsqrtf(vv.y + EPS_BN), g.y, b.y), 0.f));
  o.z = f2bf(fmaxf(fmaf((acc23.x - m.z) * rsqrtf(vv.z + EPS_BN), g.z, b.z), 0.f));
  o.w = f2bf(fmaxf(fmaf((acc23.y - m.w) * rsqrtf(vv.w + EPS_BN), g.w, b.w), 0.f));
  *(ushort4*)(h + (size_t)row * HIDD + d) = o;
}

// ---------------- SpMM2 + BN2: out = bn2(A @ z0(fp8)) ------------------------
__global__ __launch_bounds__(256) void spmm2_kernel(
    const unsigned char* __restrict__ z0, const int* __restrict__ row_start,
    const int2* __restrict__ edges,
    const float* __restrict__ gamma, const float* __restrict__ beta,
    const float* __restrict__ mean, const float* __restrict__ var,
    float* __restrict__ out) {
  const int row  = (blockIdx.x * blockDim.x + threadIdx.x) >> 6;
  const int lane = threadIdx.x & 63;
  const int s = row_start[row];
  const int e = row_start[row + 1];
  float acc = 0.f;
  int p = s;
  for (; p + 8 <= e; p += 8) {
    int2 er[8];
    unsigned char gb[8];
#pragma unroll
    for (int j = 0; j < 8; ++j) er[j] = edges[p + j];
#pragma unroll
    for (int j = 0; j < 8; ++j)
      gb[j] = z0[(size_t)(unsigned)er[j].x + lane];  // er.x = col*64
#pragma unroll
    for (int j = 0; j < 8; ++j)
      acc = fmaf(__int_as_float(er[j].y),
                 __builtin_amdgcn_cvt_f32_fp8((int)gb[j], 0), acc);
  }
  for (; p < e; ++p) {
    int2 e0 = edges[p];
    unsigned char g0 = z0[(size_t)(unsigned)e0.x + lane];
    acc = fmaf(__int_as_float(e0.y), __builtin_amdgcn_cvt_f32_fp8((int)g0, 0), acc);
  }
  float r = fmaf((acc - mean[lane]) * rsqrtf(var[lane] + EPS_BN), gamma[lane],
                 beta[lane]);
  out[(size_t)row * EMBD + lane] = r;
}

extern "C" void kernel_launch(void* const* d_in, const int* in_sizes, int n_in,
                              void* d_out, int out_size, void* d_ws, size_t ws_size,
                              hipStream_t stream) {
  const float* x        = (const float*)d_in[0];
  const int*   edge_row = (const int*)d_in[1];
  const int*   edge_col = (const int*)d_in[2];
  const float* edge_val = (const float*)d_in[3];
  const float* w1       = (const float*)d_in[4];
  const float* w2       = (const float*)d_in[5];
  const float* gamma1   = (const float*)d_in[6];
  const float* beta1    = (const float*)d_in[7];
  const float* mean1    = (const float*)d_in[8];
  const float* var1     = (const float*)d_in[9];
  const float* gamma2   = (const float*)d_in[10];
  const float* beta2    = (const float*)d_in[11];
  const float* mean2    = (const float*)d_in[12];
  const float* var2     = (const float*)d_in[13];
  float* out = (float*)d_out;

  // Workspace layout (256B aligned). Total ~110 MB.
  char* ws = (char*)d_ws;
  size_t off = 0;
  auto alloc = [&](size_t bytes) -> void* {
    void* p = ws + off;
    off = (off + bytes + 255) & ~(size_t)255;
    return p;
  };
  unsigned char*  h0  = (unsigned char*)alloc((size_t)NN * HIDD);       // 25.6MB fp8
  unsigned short* h   = (unsigned short*)alloc((size_t)NN * HIDD * 2);  // 51.2MB bf16
  // staged records alias h: 25.6MB, dead before spmm1 writes h
  unsigned long long* staged = (unsigned long long*)h;
  unsigned char*  z0  = (unsigned char*)alloc((size_t)NN * EMBD);       // 6.4MB fp8
  unsigned short* w1s = (unsigned short*)alloc((size_t)IND * HIDD * 2);
  unsigned short* w2s = (unsigned short*)alloc((size_t)HIDD * EMBD * 2);
  int*   row_start    = (int*)alloc((size_t)(NN + 1) * 4);
  int*   bcnt         = (int*)alloc((size_t)NB * 16 * 4);               // 25KB padded
  int*   bcur         = (int*)alloc((size_t)NB * 16 * 4);               // 25KB padded
  int*   bucket_start = (int*)alloc((size_t)(NB + 1) * 4);
  int2*  edges        = (int2*)alloc((size_t)EE * 8);                   // 25.6MB

  // weight swizzles (independent of CSR build)
  swz_w1_kernel<<<8192 / 256, 256, 0, stream>>>(w1, w1s);
  swz_w2_kernel<<<2048 / 256, 256, 0, stream>>>(w2, w2s);

  // CSR build: bucket hist -> bucket scan -> LDS counting-sort partition (A)
  //            -> per-bucket row_start + sort (B)
  hipMemsetAsync(bcnt, 0, (size_t)NB * 16 * 4, stream);
  histb_kernel<<<NCHUNK, 256, 0, stream>>>(edge_row, bcnt);
  bscan_kernel<<<1, 512, 0, stream>>>(bcnt, bucket_start, bcur);
  partA_kernel<<<NCHUNK, 256, 0, stream>>>(
      edge_row, edge_col, edge_val, bcur, staged);
  partB_kernel<<<NB, 256, 0, stream>>>(bucket_start, staged, edges, row_start);

  // Layer 1: h0 = fp8(bf16(x) @ w1) ; h = bf16(relu(bn1(A @ h0)))
  gemm1_mfma<<<625, 512, 0, stream>>>(x, w1s, h0);
  spmm1_kernel<<<NN / 4, 256, 0, stream>>>(h0, row_start, edges,
                                           gamma1, beta1, mean1, var1, h);
  // Layer 2: z0 = fp8(h @ w2) ; out = bn2(A @ z0)
  gemm2_mfma<<<625, 256, 0, stream>>>(h, w2s, z0);
  spmm2_kernel<<<NN / 4, 256, 0, stream>>>(z0, row_start, edges,
                                           gamma2, beta2, mean2, var2, out);
}

// Round 8
// 630.441 us; speedup vs baseline: 1.4857x; 1.0314x over previous
//
#include <hip/hip_runtime.h>
#include <hip/hip_bf16.h>

// Problem constants (from reference)
constexpr int NN   = 100000;   // nodes
constexpr int IND  = 256;      // input dim
constexpr int HIDD = 256;      // hidden dim
constexpr int EMBD = 64;       // embedding dim
constexpr int EE   = 3200000;  // edges
// CSR coarse partition: bucket = row >> CB (256 rows per bucket)
constexpr int CB    = 8;
constexpr int NB    = ((NN - 1) >> CB) + 1;   // 391
constexpr int NBP   = 512;                    // padded for LDS scan
constexpr int CHUNK = 4096;                   // edges per partA block
constexpr int EPT   = CHUNK / 256;            // 16 edges per thread
constexpr int NCHUNK = (EE + CHUNK - 1) / CHUNK;  // 782
// GEMM m-tiles per block: 2 (3125 blocks) for latency-hiding concurrency;
// 10 (625 blocks) measured latency-bound at Occupancy 27%, MfmaUtil 3% (R7).
constexpr int MT    = 2;
#define EPS_BN 1e-3f

typedef short  short8  __attribute__((ext_vector_type(8)));
typedef float  floatx4 __attribute__((ext_vector_type(4)));
typedef float  floatx2 __attribute__((ext_vector_type(2)));

static __device__ __forceinline__ unsigned short f2bf(float f) {
  __hip_bfloat16 b = __float2bfloat16(f);
  union { __hip_bfloat16 b; unsigned short u; } cv;
  cv.b = b;
  return cv.u;
}
static __device__ __forceinline__ float bf2f(unsigned short u) {
  return __uint_as_float(((unsigned)u) << 16);
}
static __device__ __forceinline__ unsigned char f2fp8(float f) {
  // v_cvt_pk_fp8_f32: OCP e4m3fn on gfx950
  return (unsigned char)__builtin_amdgcn_cvt_pk_fp8_f32(f, f, 0, false);
}

// ---- swizzle weights into MFMA B-fragment layout -----------------------------
__global__ __launch_bounds__(256) void swz_w1_kernel(
    const float* __restrict__ w1, unsigned short* __restrict__ w1s) {
  const int t = blockIdx.x * blockDim.x + threadIdx.x;  // 8192 threads
  const int lane = t & 63;
  const int f = t >> 6;          // 0..127
  const int kt = f >> 4;         // 0..7
  const int nt = f & 15;         // 0..15
  const int n = nt * 16 + (lane & 15);
#pragma unroll
  for (int j = 0; j < 8; ++j) {
    const int k = kt * 32 + (lane >> 4) * 8 + j;
    w1s[(size_t)(f * 64 + lane) * 8 + j] = f2bf(w1[k * HIDD + n]);
  }
}

__global__ __launch_bounds__(256) void swz_w2_kernel(
    const float* __restrict__ w2, unsigned short* __restrict__ w2s) {
  const int t = blockIdx.x * blockDim.x + threadIdx.x;  // 2048 threads
  const int lane = t & 63;
  const int f = t >> 6;          // 0..31
  const int kt = f >> 2;         // 0..7
  const int nt = f & 3;          // 0..3
  const int n = nt * 16 + (lane & 15);
#pragma unroll
  for (int j = 0; j < 8; ++j) {
    const int k = kt * 32 + (lane >> 4) * 8 + j;
    w2s[(size_t)(f * 64 + lane) * 8 + j] = f2bf(w2[k * EMBD + n]);
  }
}

// ---------------- GEMM1 (MFMA): h0(fp8) = bf16(x) @ w1 -----------------------
// Reads x as f32, converts in-register. 3125 blocks x MT=2 m-tiles.
__global__ __launch_bounds__(512) void gemm1_mfma(
    const float* __restrict__ x, const unsigned short* __restrict__ w1s,
    unsigned char* __restrict__ h0) {
  const int lane = threadIdx.x & 63;
  const int wave = threadIdx.x >> 6;   // 0..7
  const int quad = lane >> 4;
  const int l15  = lane & 15;
  const short8* w1v = (const short8*)w1s;
  short8 bf[2][8];
#pragma unroll
  for (int nt2 = 0; nt2 < 2; ++nt2)
#pragma unroll
    for (int kt = 0; kt < 8; ++kt)
      bf[nt2][kt] = w1v[(size_t)(kt * 16 + wave * 2 + nt2) * 64 + lane];
#pragma unroll
  for (int i = 0; i < MT; ++i) {
    const int m0 = (blockIdx.x * MT + i) * 16;
    const float* ap = x + (size_t)(m0 + l15) * IND + quad * 8;
    short8 af[8];
#pragma unroll
    for (int kt = 0; kt < 8; ++kt) {
      float4 f0 = *(const float4*)(ap + kt * 32);
      float4 f1 = *(const float4*)(ap + kt * 32 + 4);
      short8 a;
      a[0] = (short)f2bf(f0.x); a[1] = (short)f2bf(f0.y);
      a[2] = (short)f2bf(f0.z); a[3] = (short)f2bf(f0.w);
      a[4] = (short)f2bf(f1.x); a[5] = (short)f2bf(f1.y);
      a[6] = (short)f2bf(f1.z); a[7] = (short)f2bf(f1.w);
      af[kt] = a;
    }
    floatx4 c0 = {0.f, 0.f, 0.f, 0.f};
    floatx4 c1 = {0.f, 0.f, 0.f, 0.f};
#pragma unroll
    for (int kt = 0; kt < 8; ++kt) {
      c0 = __builtin_amdgcn_mfma_f32_16x16x32_bf16(af[kt], bf[0][kt], c0, 0, 0, 0);
      c1 = __builtin_amdgcn_mfma_f32_16x16x32_bf16(af[kt], bf[1][kt], c1, 0, 0, 0);
    }
    // C/D layout: col = lane&15, row = quad*4 + reg  [verified m89/m91]
    unsigned char* o = h0 + (size_t)(m0 + quad * 4) * HIDD + wave * 32 + l15;
#pragma unroll
    for (int r = 0; r < 4; ++r) {
      o[(size_t)r * HIDD]      = f2fp8(c0[r]);
      o[(size_t)r * HIDD + 16] = f2fp8(c1[r]);
    }
  }
}

// ---------------- GEMM2 (MFMA): z0(fp8) = h(bf16) @ w2 -----------------------
__global__ __launch_bounds__(256) void gemm2_mfma(
    const unsigned short* __restrict__ hb, const unsigned short* __restrict__ w2s,
    unsigned char* __restrict__ z0) {
  const int lane = threadIdx.x & 63;
  const int wave = threadIdx.x >> 6;   // 0..3
  const int quad = lane >> 4;
  const int l15  = lane & 15;
  const short8* w2v = (const short8*)w2s;
  short8 bf[8];
#pragma unroll
  for (int kt = 0; kt < 8; ++kt)
    bf[kt] = w2v[(size_t)(kt * 4 + wave) * 64 + lane];
#pragma unroll
  for (int i = 0; i < MT; ++i) {
    const int m0 = (blockIdx.x * MT + i) * 16;
    const unsigned short* ap = hb + (size_t)(m0 + l15) * HIDD + quad * 8;
    short8 af[8];
#pragma unroll
    for (int kt = 0; kt < 8; ++kt)
      af[kt] = *(const short8*)(ap + kt * 32);
    floatx4 c = {0.f, 0.f, 0.f, 0.f};
#pragma unroll
    for (int kt = 0; kt < 8; ++kt)
      c = __builtin_amdgcn_mfma_f32_16x16x32_bf16(af[kt], bf[kt], c, 0, 0, 0);
    unsigned char* o = z0 + (size_t)(m0 + quad * 4) * EMBD + wave * 16 + l15;
#pragma unroll
    for (int r = 0; r < 4; ++r) o[(size_t)r * EMBD] = f2fp8(c[r]);
  }
}

// ---------------- CSR build --------------------------------------------------
// Bucket-level histogram: LDS counters per chunk, <=NB global atomics/chunk.
__global__ __launch_bounds__(256) void histb_kernel(
    const int* __restrict__ row, int* __restrict__ bcnt) {
  __shared__ int lcnt[NB];
  for (int i = threadIdx.x; i < NB; i += 256) lcnt[i] = 0;
  __syncthreads();
  const int base = blockIdx.x * CHUNK;
  const int lim  = min(EE - base, CHUNK);
  for (int i = threadIdx.x; i < lim; i += 256)
    atomicAdd(&lcnt[row[base + i] >> CB], 1);
  __syncthreads();
  for (int i = threadIdx.x; i < NB; i += 256) {
    const int c = lcnt[i];
    if (c) atomicAdd(&bcnt[i * 16], c);
  }
}

// Scan 391 bucket counts -> bucket_start (compact) + bcur (padded cursors)
__global__ __launch_bounds__(512) void bscan_kernel(
    const int* __restrict__ bcnt, int* __restrict__ bucket_start,
    int* __restrict__ bcur) {
  __shared__ int lds[512];
  int v = (threadIdx.x < NB) ? bcnt[threadIdx.x * 16] : 0;
  lds[threadIdx.x] = v;
  for (int off = 1; off < 512; off <<= 1) {
    __syncthreads();
    int t = (threadIdx.x >= off) ? lds[threadIdx.x - off] : 0;
    __syncthreads();
    lds[threadIdx.x] += t;
  }
  __syncthreads();
  if (threadIdx.x < NB) {
    const int excl = lds[threadIdx.x] - v;
    bucket_start[threadIdx.x] = excl;
    bcur[threadIdx.x * 16] = excl;
  }
  if (threadIdx.x == 0) bucket_start[NB] = EE;
}

// Pass A: LDS counting-sort each 4096-edge chunk by coarse bucket, then flush
// piecewise-contiguous runs with ONE global atomic per (block,bucket).
// Record packs (row:17 | col:17 | val_bf16:16) into 8B.
__global__ __launch_bounds__(256) void partA_kernel(
    const int* __restrict__ row, const int* __restrict__ col,
    const float* __restrict__ val, int* __restrict__ bcur,
    unsigned long long* __restrict__ staged) {
  __shared__ unsigned long long sbuf[CHUNK];  // 32 KB
  __shared__ int cnt[NBP];
  __shared__ int scn[NBP];
  __shared__ int cur[NB];
  __shared__ int gofs[NB];
  const int base = blockIdx.x * CHUNK;
  const int lim  = min(EE - base, CHUNK);
  for (int i = threadIdx.x; i < NBP; i += 256) cnt[i] = 0;
  __syncthreads();
  // load + histogram (records kept in registers)
  unsigned long long rec[EPT];
  int bkt[EPT];
#pragma unroll
  for (int j = 0; j < EPT; ++j) {
    const int idx = threadIdx.x + j * 256;
    bkt[j] = -1;
    if (idx < lim) {
      const int e = base + idx;
      const int r = row[e];
      const int c = col[e];
      const unsigned short v = f2bf(val[e]);
      rec[j] = ((unsigned long long)r << 33) | ((unsigned long long)c << 16) | v;
      bkt[j] = r >> CB;
      atomicAdd(&cnt[bkt[j]], 1);
    }
  }
  __syncthreads();
  // inclusive scan of cnt -> scn (512 entries, 2 per thread)
  for (int i = threadIdx.x; i < NBP; i += 256) scn[i] = cnt[i];
  __syncthreads();
  for (int off = 1; off < NBP; off <<= 1) {
    const int i0 = threadIdx.x, i1 = threadIdx.x + 256;
    const int t0 = (i0 >= off) ? scn[i0 - off] : 0;
    const int t1 = (i1 >= off) ? scn[i1 - off] : 0;
    __syncthreads();
    scn[i0] += t0;
    scn[i1] += t1;
    __syncthreads();
  }
  // placement cursors = exclusive start
  for (int b = threadIdx.x; b < NB; b += 256) cur[b] = scn[b] - cnt[b];
  __syncthreads();
  // reorder into LDS (no line granularity in LDS -> scatter is fine)
#pragma unroll
  for (int j = 0; j < EPT; ++j)
    if (bkt[j] >= 0) {
      const int p = atomicAdd(&cur[bkt[j]], 1);
      sbuf[p] = rec[j];
    }
  __syncthreads();
  // reserve global ranges: one atomic per non-empty bucket
  for (int b = threadIdx.x; b < NB; b += 256) {
    const int c = cnt[b];
    const int g = (c > 0) ? atomicAdd(&bcur[b * 16], c) : 0;
    gofs[b] = g - (scn[b] - c);  // out = gofs[b] + local_slot
  }
  __syncthreads();
  // flush: consecutive slots of a bucket -> consecutive global addresses
  for (int s = threadIdx.x; s < lim; s += 256) {
    const unsigned long long rc = sbuf[s];
    const int b = (int)(rc >> (33 + CB));
    staged[(size_t)(gofs[b] + s)] = rc;
  }
}

// Pass B: one block per coarse bucket (256 rows). Pass 1 histograms rows
// (high-dword reads) -> LDS scan -> writes row_start + cursors. Pass 2
// scatters records into the block-local ~65KB window (L2-hot on re-read).
__global__ __launch_bounds__(256) void partB_kernel(
    const int* __restrict__ bucket_start,
    const unsigned long long* __restrict__ staged,
    int2* __restrict__ edges, int* __restrict__ row_start) {
  __shared__ int cnt[1 << CB];
  __shared__ int ofs[1 << CB];
  const int b  = blockIdx.x;
  const int r0 = b << CB;
  const int rn = min(NN - r0, 1 << CB);
  const int s  = bucket_start[b];
  const int e  = bucket_start[b + 1];
  cnt[threadIdx.x] = 0;
  __syncthreads();
  // pass 1: row histogram (read only the high dword of each record)
  const unsigned* hi = (const unsigned*)staged;
  for (int p = s + threadIdx.x; p < e; p += 256) {
    const unsigned hw = hi[2 * p + 1];
    const int r = (int)((hw >> 1) & 0x1FFFF);
    atomicAdd(&cnt[r - r0], 1);
  }
  __syncthreads();
  // exclusive scan of 256 bins
  const int v = cnt[threadIdx.x];
  ofs[threadIdx.x] = v;
  for (int off = 1; off < 256; off <<= 1) {
    __syncthreads();
    const int t = (threadIdx.x >= off) ? ofs[threadIdx.x - off] : 0;
    __syncthreads();
    ofs[threadIdx.x] += t;
  }
  __syncthreads();
  const int excl = ofs[threadIdx.x] - v;
  if ((int)threadIdx.x < rn) row_start[r0 + threadIdx.x] = s + excl;
  if (b == NB - 1 && threadIdx.x == 0) row_start[NN] = e;
  __syncthreads();
  cnt[threadIdx.x] = s + excl;  // reuse as cursors
  __syncthreads();
  // pass 2: scatter into final CSR order
  for (int p = s + threadIdx.x; p < e; p += 256) {
    const unsigned long long rc = staged[p];
    const int r = (int)(rc >> 33);
    const int c = (int)((rc >> 16) & 0x1FFFF);
    const float vv = bf2f((unsigned short)(rc & 0xFFFF));
    const int q = atomicAdd(&cnt[r - r0], 1);
    int2 pk; pk.x = c << 6; pk.y = __float_as_int(vv);  // col*64 pre-scaled
    edges[q] = pk;
  }
}

// ---------------- SpMM1 + BN1 + ReLU: h(bf16) = relu(bn1(A @ h0(fp8))) -------
__global__ __launch_bounds__(256) void spmm1_kernel(
    const unsigned char* __restrict__ h0, const int* __restrict__ row_start,
    const int2* __restrict__ edges,
    const float* __restrict__ gamma, const float* __restrict__ beta,
    const float* __restrict__ mean, const float* __restrict__ var,
    unsigned short* __restrict__ h) {
  const int row  = (blockIdx.x * blockDim.x + threadIdx.x) >> 6;
  const int lane = threadIdx.x & 63;
  const int lane4 = lane * 4;
  const int s = row_start[row];
  const int e = row_start[row + 1];
  floatx2 acc01 = {0.f, 0.f};
  floatx2 acc23 = {0.f, 0.f};
  int p = s;
  for (; p + 8 <= e; p += 8) {
    int2 er[8];
    unsigned gg[8];
#pragma unroll
    for (int j = 0; j < 8; ++j) er[j] = edges[p + j];
#pragma unroll
    for (int j = 0; j < 8; ++j)
      gg[j] = *(const unsigned*)(h0 + ((size_t)(unsigned)er[j].x * 4) + lane4);
#pragma unroll
    for (int j = 0; j < 8; ++j) {
      const float v = __int_as_float(er[j].y);
      floatx2 lo = __builtin_amdgcn_cvt_pk_f32_fp8(gg[j], false);
      floatx2 hi = __builtin_amdgcn_cvt_pk_f32_fp8(gg[j], true);
      acc01 += lo * v;
      acc23 += hi * v;
    }
  }
  for (; p < e; ++p) {
    int2 e0 = edges[p];
    unsigned g0 = *(const unsigned*)(h0 + ((size_t)(unsigned)e0.x * 4) + lane4);
    const float v0 = __int_as_float(e0.y);
    floatx2 lo = __builtin_amdgcn_cvt_pk_f32_fp8(g0, false);
    floatx2 hi = __builtin_amdgcn_cvt_pk_f32_fp8(g0, true);
    acc01 += lo * v0;
    acc23 += hi * v0;
  }
  const int d = lane4;
  float4 g = *(const float4*)(gamma + d);
  float4 b = *(const float4*)(beta + d);
  float4 m = *(const float4*)(mean + d);
  float4 vv = *(const float4*)(var + d);
  ushort4 o;
  o.x = f2bf(fmaxf(fmaf((acc01.x - m.x) * rsqrtf(vv.x + EPS_BN), g.x, b.x), 0.f));
  o.y = f2bf(fmaxf(fmaf((acc01.y - m.y) * rsqrtf(vv.y + EPS_BN), g.y, b.y), 0.f));
  o.z = f2bf(fmaxf(fmaf((acc23.x - m.z) * rsqrtf(vv.z + EPS_BN), g.z, b.z), 0.f));
  o.w = f2bf(fmaxf(fmaf((acc23.y - m.w) * rsqrtf(vv.w + EPS_BN), g.w, b.w), 0.f));
  *(ushort4*)(h + (size_t)row * HIDD + d) = o;
}

// ---------------- SpMM2 + BN2: out = bn2(A @ z0(fp8)) ------------------------
__global__ __launch_bounds__(256) void spmm2_kernel(
    const unsigned char* __restrict__ z0, const int* __restrict__ row_start,
    const int2* __restrict__ edges,
    const float* __restrict__ gamma, const float* __restrict__ beta,
    const float* __restrict__ mean, const float* __restrict__ var,
    float* __restrict__ out) {
  const int row  = (blockIdx.x * blockDim.x + threadIdx.x) >> 6;
  const int lane = threadIdx.x & 63;
  const int s = row_start[row];
  const int e = row_start[row + 1];
  float acc = 0.f;
  int p = s;
  for (; p + 8 <= e; p += 8) {
    int2 er[8];
    unsigned char gb[8];
#pragma unroll
    for (int j = 0; j < 8; ++j) er[j] = edges[p + j];
#pragma unroll
    for (int j = 0; j < 8; ++j)
      gb[j] = z0[(size_t)(unsigned)er[j].x + lane];  // er.x = col*64
#pragma unroll
    for (int j = 0; j < 8; ++j)
      acc = fmaf(__int_as_float(er[j].y),
                 __builtin_amdgcn_cvt_f32_fp8((int)gb[j], 0), acc);
  }
  for (; p < e; ++p) {
    int2 e0 = edges[p];
    unsigned char g0 = z0[(size_t)(unsigned)e0.x + lane];
    acc = fmaf(__int_as_float(e0.y), __builtin_amdgcn_cvt_f32_fp8((int)g0, 0), acc);
  }
  float r = fmaf((acc - mean[lane]) * rsqrtf(var[lane] + EPS_BN), gamma[lane],
                 beta[lane]);
  out[(size_t)row * EMBD + lane] = r;
}

extern "C" void kernel_launch(void* const* d_in, const int* in_sizes, int n_in,
                              void* d_out, int out_size, void* d_ws, size_t ws_size,
                              hipStream_t stream) {
  const float* x        = (const float*)d_in[0];
  const int*   edge_row = (const int*)d_in[1];
  const int*   edge_col = (const int*)d_in[2];
  const float* edge_val = (const float*)d_in[3];
  const float* w1       = (const float*)d_in[4];
  const float* w2       = (const float*)d_in[5];
  const float* gamma1   = (const float*)d_in[6];
  const float* beta1    = (const float*)d_in[7];
  const float* mean1    = (const float*)d_in[8];
  const float* var1     = (const float*)d_in[9];
  const float* gamma2   = (const float*)d_in[10];
  const float* beta2    = (const float*)d_in[11];
  const float* mean2    = (const float*)d_in[12];
  const float* var2     = (const float*)d_in[13];
  float* out = (float*)d_out;

  // Workspace layout (256B aligned). Total ~110 MB.
  char* ws = (char*)d_ws;
  size_t off = 0;
  auto alloc = [&](size_t bytes) -> void* {
    void* p = ws + off;
    off = (off + bytes + 255) & ~(size_t)255;
    return p;
  };
  unsigned char*  h0  = (unsigned char*)alloc((size_t)NN * HIDD);       // 25.6MB fp8
  unsigned short* h   = (unsigned short*)alloc((size_t)NN * HIDD * 2);  // 51.2MB bf16
  // staged records alias h: 25.6MB, dead before spmm1 writes h
  unsigned long long* staged = (unsigned long long*)h;
  unsigned char*  z0  = (unsigned char*)alloc((size_t)NN * EMBD);       // 6.4MB fp8
  unsigned short* w1s = (unsigned short*)alloc((size_t)IND * HIDD * 2);
  unsigned short* w2s = (unsigned short*)alloc((size_t)HIDD * EMBD * 2);
  int*   row_start    = (int*)alloc((size_t)(NN + 1) * 4);
  int*   bcnt         = (int*)alloc((size_t)NB * 16 * 4);               // 25KB padded
  int*   bcur         = (int*)alloc((size_t)NB * 16 * 4);               // 25KB padded
  int*   bucket_start = (int*)alloc((size_t)(NB + 1) * 4);
  int2*  edges        = (int2*)alloc((size_t)EE * 8);                   // 25.6MB

  // weight swizzles (independent of CSR build)
  swz_w1_kernel<<<8192 / 256, 256, 0, stream>>>(w1, w1s);
  swz_w2_kernel<<<2048 / 256, 256, 0, stream>>>(w2, w2s);

  // CSR build: bucket hist -> bucket scan -> LDS counting-sort partition (A)
  //            -> per-bucket row_start + sort (B)
  hipMemsetAsync(bcnt, 0, (size_t)NB * 16 * 4, stream);
  histb_kernel<<<NCHUNK, 256, 0, stream>>>(edge_row, bcnt);
  bscan_kernel<<<1, 512, 0, stream>>>(bcnt, bucket_start, bcur);
  partA_kernel<<<NCHUNK, 256, 0, stream>>>(
      edge_row, edge_col, edge_val, bcur, staged);
  partB_kernel<<<NB, 256, 0, stream>>>(bucket_start, staged, edges, row_start);

  // Layer 1: h0 = fp8(bf16(x) @ w1) ; h = bf16(relu(bn1(A @ h0)))
  gemm1_mfma<<<NN / (16 * MT), 512, 0, stream>>>(x, w1s, h0);
  spmm1_kernel<<<NN / 4, 256, 0, stream>>>(h0, row_start, edges,
                                           gamma1, beta1, mean1, var1, h);
  // Layer 2: z0 = fp8(h @ w2) ; out = bn2(A @ z0)
  gemm2_mfma<<<NN / (16 * MT), 256, 0, stream>>>(h, w2s, z0);
  spmm2_kernel<<<NN / 4, 256, 0, stream>>>(z0, row_start, edges,
                                           gamma2, beta2, mean2, var2, out);
}